// Round 1
// baseline (634.224 us; speedup 1.0000x reference)
//
#include <hip/hip_runtime.h>
#include <stdint.h>

typedef unsigned short u16;
typedef unsigned int u32;
typedef unsigned long long u64;
typedef __attribute__((ext_vector_type(8))) __bf16 bf16x8;
typedef __attribute__((ext_vector_type(4))) float f32x4;

#define DEVI __device__ __forceinline__

DEVI u16 f2bf(float f) {                    // fp32 -> bf16 RNE
  u32 u = __float_as_uint(f);
  u += 0x7FFFu + ((u >> 16) & 1u);
  return (u16)(u >> 16);
}
DEVI float bf2f(u16 h) { return __uint_as_float(((u32)h) << 16); }

DEVI float wredf(float v) {
  #pragma unroll
  for (int m = 32; m; m >>= 1) v += __shfl_xor(v, m, 64);
  return v;
}
DEVI int wredi(int v) {
  #pragma unroll
  for (int m = 32; m; m >>= 1) v += __shfl_xor(v, m, 64);
  return v;
}

DEVI void glds16(const void* g, void* l) {  // 16B-per-lane global->LDS DMA
  __builtin_amdgcn_global_load_lds((const __attribute__((address_space(1))) void*)g,
                                   (__attribute__((address_space(3))) void*)l, 16, 0, 0);
}

// ---------------- prep: pack (x,y,z,||x||^2) per point ----------------
__global__ void k_pack_coords(const float* __restrict__ x, float4* __restrict__ c4) {
  int g = blockIdx.x * 256 + threadIdx.x;          // < 16384
  float x0 = x[g*3], x1 = x[g*3+1], x2 = x[g*3+2];
  float n = __fadd_rn(__fadd_rn(__fmul_rn(x0,x0), __fmul_rn(x1,x1)), __fmul_rn(x2,x2));
  c4[g] = make_float4(x0, x1, x2, n);
}

// ---------------- prep: all MFMA weights -> bf16 (a/b stacked) ----------------
__global__ void k_pack_w(const float* __restrict__ w2a, const float* __restrict__ w2b,
                         const float* __restrict__ w3a, const float* __restrict__ w3b,
                         const float* __restrict__ w4a, const float* __restrict__ w4b,
                         const float* __restrict__ w51, const float* __restrict__ w52,
                         u16* __restrict__ wbf) {
  int g = blockIdx.x * 256 + threadIdx.x;          // < 1,138,688 exact
  const float* s; int off;
  if      (g <    4096) { s = w2a; off = g; }
  else if (g <    8192) { s = w2b; off = g - 4096; }
  else if (g <   16384) { s = w3a; off = g - 8192; }
  else if (g <   24576) { s = w3b; off = g - 16384; }
  else if (g <   57344) { s = w4a; off = g - 24576; }
  else if (g <   90112) { s = w4b; off = g - 57344; }
  else if (g <  614400) { s = w51; off = g - 90112; }
  else                  { s = w52; off = g - 614400; }
  wbf[g] = f2bf(s[off]);
}

// ---------------- knn: per-row top-80 (sorted desc, ties by low index) ----------------
__global__ __launch_bounds__(64) void k_knn(const float4* __restrict__ c4, int* __restrict__ idxp) {
  __shared__ u64 cand[128];
  __shared__ int scnt;
  const int blk = blockIdx.x;                       // b*2048 + n
  const int lane = threadIdx.x;
  const int b = blk >> 11;
  const float4* cb = c4 + (b << 11);
  const float4 q = cb[blk & 2047];

  u32 key[32];
  #pragma unroll
  for (int s = 0; s < 32; ++s) {
    float4 c = cb[s*64 + lane];
    // match reference rounding: inner=((x0y0+x1y1)+x2y2); pd=(2*inner - xn2) - xm2 ; no fma
    float inner = __fadd_rn(__fadd_rn(__fmul_rn(q.x,c.x), __fmul_rn(q.y,c.y)), __fmul_rn(q.z,c.z));
    float pd = __fsub_rn(__fsub_rn(__fmul_rn(2.0f, inner), q.w), c.w);
    u32 bits = __float_as_uint(pd);
    key[s] = (bits & 0x80000000u) ? ~bits : (bits | 0x80000000u);
  }
  // radix-bisect the 80th-largest key value
  u32 T = 0;
  for (int bit = 30; bit >= 0; --bit) {
    u32 Tc = T | (1u << bit);
    int c = 0;
    #pragma unroll
    for (int s = 0; s < 32; ++s) c += (key[s] >= Tc) ? 1 : 0;
    c = wredi(c);
    if (c >= 80) { T = Tc; if (c == 80) break; }
  }
  if (lane == 0) scnt = 0;
  __syncthreads();
  #pragma unroll
  for (int s = 0; s < 32; ++s) {
    if (key[s] >= T) {
      int p = atomicAdd(&scnt, 1);
      if (p < 128) cand[p] = (((u64)key[s]) << 32) | (u32)(2047 - (s*64 + lane));
    }
  }
  __syncthreads();
  int total = scnt; if (total > 128) total = 128;
  for (int i = lane; i < 128; i += 64) if (i >= total) cand[i] = 0ull;
  __syncthreads();
  // bitonic sort 128, descending by (key, then 2047-idx) => ties give smaller idx first
  #pragma unroll
  for (int k2 = 2; k2 <= 128; k2 <<= 1) {
    #pragma unroll
    for (int j = k2 >> 1; j > 0; j >>= 1) {
      int i = ((lane / j) * 2 * j) + (lane % j);
      int p = i + j;
      u64 a = cand[i], c = cand[p];
      bool desc = ((i & k2) == 0);
      if ((a < c) == desc) { cand[i] = c; cand[p] = a; }
      __syncthreads();
    }
  }
  #pragma unroll
  for (int t = lane; t < 80; t += 64) {
    u32 low = (u32)cand[t];
    idxp[blk*80 + t] = 2047 - (int)low;
  }
}

// ---------------- layer 1 conv (K=3, fp32 exact) -> bf16, both a&b paths ----------------
__global__ void k_conv1(const float* __restrict__ x, const float* __restrict__ w1a,
                        const float* __restrict__ w1b, u16* __restrict__ out) {
  int g = blockIdx.x * 256 + threadIdx.x;          // < 16384*128
  int m = g >> 7, o = g & 127;
  const float* w = (o < 64) ? (w1a + 3*o) : (w1b + 3*(o-64));
  const float* xm = x + 3*m;
  float acc = w[0]*xm[0] + w[1]*xm[1] + w[2]*xm[2];
  out[g] = f2bf(acc);
}

// ---------------- GroupNorm stats (one block per (b,group), deterministic) ----------------
__global__ __launch_bounds__(256) void k_stats_bf(const u16* __restrict__ act, int CtotShift,
                                                  int CgShift, int NG, float2* __restrict__ stats) {
  int b = blockIdx.x / NG, g = blockIdx.x % NG;
  int w4s = CgShift - 2;
  int count4 = 2048 << w4s;
  float s = 0.f, ss = 0.f;
  const u16* base = act + (((size_t)(b << 11)) << CtotShift) + ((size_t)g << CgShift);
  for (int i = threadIdx.x; i < count4; i += 256) {
    int n = i >> w4s, cw = i & ((1 << w4s) - 1);
    ushort4 v = *(const ushort4*)(base + (((size_t)n) << CtotShift) + cw*4);
    float a0 = bf2f(v.x), a1 = bf2f(v.y), a2 = bf2f(v.z), a3 = bf2f(v.w);
    s  += a0 + a1 + a2 + a3;
    ss += a0*a0 + a1*a1 + a2*a2 + a3*a3;
  }
  s = wredf(s); ss = wredf(ss);
  __shared__ float red[8];
  int wid = threadIdx.x >> 6;
  if ((threadIdx.x & 63) == 0) { red[wid*2] = s; red[wid*2+1] = ss; }
  __syncthreads();
  if (threadIdx.x == 0) {
    float S = red[0]+red[2]+red[4]+red[6], SS = red[1]+red[3]+red[5]+red[7];
    float cnt = (float)(2048 << CgShift);
    float mean = S / cnt;
    float var = SS / cnt - mean*mean;
    stats[blockIdx.x] = make_float2(mean, rsqrtf(var + 1e-5f));
  }
}

__global__ __launch_bounds__(256) void k_stats_f32(const float* __restrict__ act, int CtotShift,
                                                   int CgShift, int NG, float2* __restrict__ stats) {
  int b = blockIdx.x / NG, g = blockIdx.x % NG;
  int w4s = CgShift - 2;
  int count4 = 2048 << w4s;
  float s = 0.f, ss = 0.f;
  const float* base = act + (((size_t)(b << 11)) << CtotShift) + ((size_t)g << CgShift);
  for (int i = threadIdx.x; i < count4; i += 256) {
    int n = i >> w4s, cw = i & ((1 << w4s) - 1);
    float4 v = *(const float4*)(base + (((size_t)n) << CtotShift) + cw*4);
    s  += v.x + v.y + v.z + v.w;
    ss += v.x*v.x + v.y*v.y + v.z*v.z + v.w*v.w;
  }
  s = wredf(s); ss = wredf(ss);
  __shared__ float red[8];
  int wid = threadIdx.x >> 6;
  if ((threadIdx.x & 63) == 0) { red[wid*2] = s; red[wid*2+1] = ss; }
  __syncthreads();
  if (threadIdx.x == 0) {
    float S = red[0]+red[2]+red[4]+red[6], SS = red[1]+red[3]+red[5]+red[7];
    float cnt = (float)(2048 << CgShift);
    float mean = S / cnt;
    float var = SS / cnt - mean*mean;
    stats[blockIdx.x] = make_float2(mean, rsqrtf(var + 1e-5f));
  }
}

// ---------------- GN apply + LeakyReLU, in place (bf16), split gamma/beta a|b ----------------
__global__ __launch_bounds__(256) void k_apply_bf(u16* __restrict__ act, int CtotShift, int CgShift,
    int NG, const float2* __restrict__ stats, const float* __restrict__ ga, const float* __restrict__ ba,
    const float* __restrict__ gb, const float* __restrict__ bb, int Ca) {
  int gid = blockIdx.x * 256 + threadIdx.x;
  size_t e = (size_t)gid * 8;
  int Ctot = 1 << CtotShift;
  int row = (int)(e >> CtotShift);
  int c = (int)e & (Ctot - 1);
  int g = c >> CgShift;
  float2 st = stats[(row >> 11) * NG + g];
  uint4 v = *(const uint4*)(act + e);
  u32 vv[4] = {v.x, v.y, v.z, v.w};
  #pragma unroll
  for (int q2 = 0; q2 < 4; ++q2) {
    int c0 = c + q2*2, c1 = c0 + 1;
    float x0 = bf2f((u16)(vv[q2] & 0xFFFF));
    float x1 = bf2f((u16)(vv[q2] >> 16));
    float G0 = (c0 < Ca) ? ga[c0] : gb[c0 - Ca];
    float B0 = (c0 < Ca) ? ba[c0] : bb[c0 - Ca];
    float G1 = (c1 < Ca) ? ga[c1] : gb[c1 - Ca];
    float B1 = (c1 < Ca) ? ba[c1] : bb[c1 - Ca];
    float h0 = (x0 - st.x) * st.y * G0 + B0;
    float h1 = (x1 - st.x) * st.y * G1 + B1;
    h0 = h0 > 0.f ? h0 : 0.2f * h0;
    h1 = h1 > 0.f ? h1 : 0.2f * h1;
    vv[q2] = (u32)f2bf(h0) | (((u32)f2bf(h1)) << 16);
  }
  *(uint4*)(act + e) = make_uint4(vv[0], vv[1], vv[2], vv[3]);
}

__global__ __launch_bounds__(256) void k_apply_f32(float* __restrict__ act, int NG, int CgShift,
    const float2* __restrict__ stats, const float* __restrict__ ga, const float* __restrict__ ba) {
  int gid = blockIdx.x * 256 + threadIdx.x;
  size_t e = (size_t)gid * 4;
  int row = (int)(e >> 9);               // Ctot = 512
  int c = (int)e & 511;
  int g = c >> CgShift;
  float2 st = stats[(row >> 11) * NG + g];
  float4 v = *(const float4*)(act + e);
  float h[4] = {v.x, v.y, v.z, v.w};
  #pragma unroll
  for (int q = 0; q < 4; ++q) {
    float xn = (h[q] - st.x) * st.y;
    float o = xn * ga[c+q] + ba[c+q];
    h[q] = o > 0.f ? o : 0.2f * o;
  }
  *(float4*)(act + e) = make_float4(h[0], h[1], h[2], h[3]);
}

// ---------------- gather-max over k neighbors + add fb -> xcat slice ----------------
__global__ __launch_bounds__(256) void k_gather(const u16* __restrict__ conv, int Ctot, int Ca,
    const int* __restrict__ idxp, int k, u16* __restrict__ xcat, int outOff, int lppShift) {
  int gid = blockIdx.x * 256 + threadIdx.x;
  int p = gid >> lppShift;
  int c4 = (gid & ((1 << lppShift) - 1)) * 4;
  int b = p >> 11;
  const int* irow = idxp + (size_t)p * 80;
  float m0 = -3.4e38f, m1 = m0, m2 = m0, m3 = m0;
  const u16* cb = conv + ((size_t)(b << 11)) * Ctot + c4;
  for (int j = 0; j < k; ++j) {
    int mi = irow[j];
    ushort4 v = *(const ushort4*)(cb + (size_t)mi * Ctot);
    m0 = fmaxf(m0, bf2f(v.x)); m1 = fmaxf(m1, bf2f(v.y));
    m2 = fmaxf(m2, bf2f(v.z)); m3 = fmaxf(m3, bf2f(v.w));
  }
  ushort4 fbv = *(const ushort4*)(conv + (size_t)p * Ctot + Ca + c4);
  m0 += bf2f(fbv.x); m1 += bf2f(fbv.y); m2 += bf2f(fbv.z); m3 += bf2f(fbv.w);
  ushort4 o;
  o.x = f2bf(m0); o.y = f2bf(m1); o.z = f2bf(m2); o.w = f2bf(m3);
  *(ushort4*)(xcat + (size_t)p * 512 + outOff + c4) = o;
}

// ---------------- bf16 MFMA GEMM: C[M x N] = A[M x K] * W[N x K]^T ----------------
template<int OUTF32>
__global__ __launch_bounds__(256) void k_gemm(const u16* __restrict__ A, int lda,
    const u16* __restrict__ Bw, int K, void* __restrict__ outp, int ldc) {
  constexpr int BK = 64;
  __shared__ __align__(16) u16 As[128 * BK];
  __shared__ __align__(16) u16 Bs[128 * BK];
  const int tid = threadIdx.x;
  const int wid = tid >> 6, lane = tid & 63;
  const int tileM = blockIdx.x * 128, tileN = blockIdx.y * 128;
  const int wm = wid >> 1, wn = wid & 1;           // 2x2 waves, 64x64 each
  const int lr = lane & 15, lk = (lane >> 4) * 8;
  f32x4 acc[4][4] = {};
  for (int k0 = 0; k0 < K; k0 += BK) {
    __syncthreads();
    #pragma unroll
    for (int i = 0; i < 4; ++i) {
      int flat = i * 256 + tid;
      int row = flat >> 3, ck = flat & 7;
      glds16(A + (size_t)(tileM + row) * lda + (k0 + ck * 8), (char*)As + flat * 16);
    }
    #pragma unroll
    for (int i = 0; i < 4; ++i) {
      int flat = i * 256 + tid;
      int row = flat >> 3, ck = flat & 7;
      glds16(Bw + (size_t)(tileN + row) * K + (k0 + ck * 8), (char*)Bs + flat * 16);
    }
    __syncthreads();                                // drains vmcnt before barrier
    #pragma unroll
    for (int ks = 0; ks < 2; ++ks) {
      bf16x8 af[4], bfr[4];
      #pragma unroll
      for (int i = 0; i < 4; ++i)
        af[i] = *(const bf16x8*)&As[(wm*64 + i*16 + lr) * BK + ks*32 + lk];
      #pragma unroll
      for (int j = 0; j < 4; ++j)
        bfr[j] = *(const bf16x8*)&Bs[(wn*64 + j*16 + lr) * BK + ks*32 + lk];
      #pragma unroll
      for (int i = 0; i < 4; ++i)
        #pragma unroll
        for (int j = 0; j < 4; ++j)
          acc[i][j] = __builtin_amdgcn_mfma_f32_16x16x32_bf16(af[i], bfr[j], acc[i][j], 0, 0, 0);
    }
  }
  const int orow0 = tileM + wm*64 + ((lane >> 4) * 4);
  const int ocol0 = tileN + wn*64 + lr;
  #pragma unroll
  for (int i = 0; i < 4; ++i)
    #pragma unroll
    for (int j = 0; j < 4; ++j)
      #pragma unroll
      for (int r = 0; r < 4; ++r) {
        int row = orow0 + i*16 + r;
        int col = ocol0 + j*16;
        float v = acc[i][j][r];
        if (OUTF32) ((float*)outp)[(size_t)row * ldc + col] = v;
        else        ((u16*)outp)[(size_t)row * ldc + col] = f2bf(v);
      }
}

// ---------------- launch ----------------
extern "C" void kernel_launch(void* const* d_in, const int* in_sizes, int n_in,
                              void* d_out, int out_size, void* d_ws, size_t ws_size,
                              hipStream_t stream) {
  const float* x   = (const float*)d_in[0];
  const float* w1a = (const float*)d_in[1];
  const float* g1a = (const float*)d_in[2];
  const float* b1a = (const float*)d_in[3];
  const float* w1b = (const float*)d_in[4];
  const float* g1b = (const float*)d_in[5];
  const float* b1b = (const float*)d_in[6];
  const float* w2a = (const float*)d_in[7];
  const float* g2a = (const float*)d_in[8];
  const float* b2a = (const float*)d_in[9];
  const float* w2b = (const float*)d_in[10];
  const float* g2b = (const float*)d_in[11];
  const float* b2b = (const float*)d_in[12];
  const float* w3a = (const float*)d_in[13];
  const float* g3a = (const float*)d_in[14];
  const float* b3a = (const float*)d_in[15];
  const float* w3b = (const float*)d_in[16];
  const float* g3b = (const float*)d_in[17];
  const float* b3b = (const float*)d_in[18];
  const float* w4a = (const float*)d_in[19];
  const float* g4a = (const float*)d_in[20];
  const float* b4a = (const float*)d_in[21];
  const float* w4b = (const float*)d_in[22];
  const float* g4b = (const float*)d_in[23];
  const float* b4b = (const float*)d_in[24];
  const float* w51 = (const float*)d_in[25];
  const float* g51 = (const float*)d_in[26];
  const float* b51 = (const float*)d_in[27];
  const float* w52 = (const float*)d_in[28];
  const float* g52 = (const float*)d_in[29];
  const float* b52 = (const float*)d_in[30];

  char* ws = (char*)d_ws;                           // ~75 MB used
  int*    idxp   = (int*)   (ws + 0);               // 16384*80*4   = 5,242,880
  float4* c4     = (float4*)(ws + 5242880);         // 16384*16     = 262,144
  u16*    wbf    = (u16*)   (ws + 5505024);         // 1,138,688*2  = 2,277,376
  float2* stats  = (float2*)(ws + 7782400);         // 256*8        = 2,048
  u16*    convAB = (u16*)   (ws + 7784448);         // 16 MB
  u16*    h1     = (u16*)   (ws + 24561664);        // 32 MB
  u16*    xcat   = (u16*)   (ws + 58116096);        // 16 MB
  u16* wc2 = wbf, *wc3 = wbf + 8192, *wc4 = wbf + 24576;
  u16* w51b = wbf + 90112, *w52b = wbf + 614400;
  float* outf = (float*)d_out;

  k_pack_coords<<<64, 256, 0, stream>>>(x, c4);
  k_pack_w<<<4448, 256, 0, stream>>>(w2a, w2b, w3a, w3b, w4a, w4b, w51, w52, wbf);
  k_knn<<<16384, 64, 0, stream>>>(c4, idxp);

  // layer 1 (3->64 x2, groups 8 each => combined 16 groups of 8)
  k_conv1<<<8192, 256, 0, stream>>>(x, w1a, w1b, convAB);
  k_stats_bf<<<128, 256, 0, stream>>>(convAB, 7, 3, 16, stats);
  k_apply_bf<<<1024, 256, 0, stream>>>(convAB, 7, 3, 16, stats, g1a, b1a, g1b, b1b, 64);
  k_gather<<<1024, 256, 0, stream>>>(convAB, 128, 64, idxp, 20, xcat, 0, 4);

  // layer 2 (64->64 x2)
  k_gemm<0><<<dim3(128,1), 256, 0, stream>>>(xcat + 0, 512, wc2, 64, convAB, 128);
  k_stats_bf<<<128, 256, 0, stream>>>(convAB, 7, 3, 16, stats);
  k_apply_bf<<<1024, 256, 0, stream>>>(convAB, 7, 3, 16, stats, g2a, b2a, g2b, b2b, 64);
  k_gather<<<1024, 256, 0, stream>>>(convAB, 128, 64, idxp, 40, xcat, 64, 4);

  // layer 3 (64->128 x2, groups 8 => Cg 16, combined 16 groups)
  k_gemm<0><<<dim3(128,2), 256, 0, stream>>>(xcat + 64, 512, wc3, 64, convAB, 256);
  k_stats_bf<<<128, 256, 0, stream>>>(convAB, 8, 4, 16, stats);
  k_apply_bf<<<2048, 256, 0, stream>>>(convAB, 8, 4, 16, stats, g3a, b3a, g3b, b3b, 128);
  k_gather<<<2048, 256, 0, stream>>>(convAB, 256, 128, idxp, 60, xcat, 128, 5);

  // layer 4 (128->256 x2, groups 16 => Cg 16, combined 32 groups)
  k_gemm<0><<<dim3(128,4), 256, 0, stream>>>(xcat + 128, 512, wc4, 128, convAB, 512);
  k_stats_bf<<<256, 256, 0, stream>>>(convAB, 9, 4, 32, stats);
  k_apply_bf<<<4096, 256, 0, stream>>>(convAB, 9, 4, 32, stats, g4a, b4a, g4b, b4b, 256);
  k_gather<<<4096, 256, 0, stream>>>(convAB, 512, 256, idxp, 80, xcat, 256, 6);

  // layer 5_1 (512->1024, groups 16 => Cg 64)
  k_gemm<0><<<dim3(128,8), 256, 0, stream>>>(xcat, 512, w51b, 512, h1, 1024);
  k_stats_bf<<<128, 256, 0, stream>>>(h1, 10, 6, 16, stats);
  k_apply_bf<<<8192, 256, 0, stream>>>(h1, 10, 6, 16, stats, g51, b51, g51, b51, 1024);

  // layer 5_2 (1024->512, groups 16 => Cg 32), fp32 out in d_out, GN+LReLU in place
  k_gemm<1><<<dim3(128,4), 256, 0, stream>>>(h1, 1024, w52b, 1024, (void*)outf, 512);
  k_stats_f32<<<128, 256, 0, stream>>>(outf, 9, 5, 16, stats);
  k_apply_f32<<<8192, 256, 0, stream>>>(outf, 16, 5, stats, g52, b52);
}

// Round 2
// 523.265 us; speedup vs baseline: 1.2121x; 1.2121x over previous
//
#include <hip/hip_runtime.h>
#include <stdint.h>

typedef unsigned short u16;
typedef unsigned int u32;
typedef unsigned long long u64;
typedef __attribute__((ext_vector_type(8))) __bf16 bf16x8;
typedef __attribute__((ext_vector_type(4))) float f32x4;

#define DEVI __device__ __forceinline__

DEVI u16 f2bf(float f) {                    // fp32 -> bf16 RNE
  u32 u = __float_as_uint(f);
  u += 0x7FFFu + ((u >> 16) & 1u);
  return (u16)(u >> 16);
}
DEVI float bf2f(u16 h) { return __uint_as_float(((u32)h) << 16); }

DEVI float wredf(float v) {
  #pragma unroll
  for (int m = 32; m; m >>= 1) v += __shfl_xor(v, m, 64);
  return v;
}
DEVI int wredi(int v) {
  #pragma unroll
  for (int m = 32; m; m >>= 1) v += __shfl_xor(v, m, 64);
  return v;
}

DEVI void glds16(const void* g, void* l) {  // 16B-per-lane global->LDS DMA
  __builtin_amdgcn_global_load_lds((const __attribute__((address_space(1))) void*)g,
                                   (__attribute__((address_space(3))) void*)l, 16, 0, 0);
}

// ---------------- prep: pack (x,y,z,||x||^2) per point ----------------
__global__ void k_pack_coords(const float* __restrict__ x, float4* __restrict__ c4) {
  int g = blockIdx.x * 256 + threadIdx.x;          // < 16384
  float x0 = x[g*3], x1 = x[g*3+1], x2 = x[g*3+2];
  float n = __fadd_rn(__fadd_rn(__fmul_rn(x0,x0), __fmul_rn(x1,x1)), __fmul_rn(x2,x2));
  c4[g] = make_float4(x0, x1, x2, n);
}

// ---------------- prep: all MFMA weights -> bf16 (a/b stacked) ----------------
__global__ void k_pack_w(const float* __restrict__ w2a, const float* __restrict__ w2b,
                         const float* __restrict__ w3a, const float* __restrict__ w3b,
                         const float* __restrict__ w4a, const float* __restrict__ w4b,
                         const float* __restrict__ w51, const float* __restrict__ w52,
                         u16* __restrict__ wbf) {
  int g = blockIdx.x * 256 + threadIdx.x;          // < 1,138,688 exact
  const float* s; int off;
  if      (g <    4096) { s = w2a; off = g; }
  else if (g <    8192) { s = w2b; off = g - 4096; }
  else if (g <   16384) { s = w3a; off = g - 8192; }
  else if (g <   24576) { s = w3b; off = g - 16384; }
  else if (g <   57344) { s = w4a; off = g - 24576; }
  else if (g <   90112) { s = w4b; off = g - 57344; }
  else if (g <  614400) { s = w51; off = g - 90112; }
  else                  { s = w52; off = g - 614400; }
  wbf[g] = f2bf(s[off]);
}

// ---------------- knn: per-row top-80 (sorted desc, ties by low index) ----------------
__global__ __launch_bounds__(64) void k_knn(const float4* __restrict__ c4, int* __restrict__ idxp) {
  __shared__ u64 cand[128];
  __shared__ int scnt;
  const int blk = blockIdx.x;                       // b*2048 + n
  const int lane = threadIdx.x;
  const int b = blk >> 11;
  const float4* cb = c4 + (b << 11);
  const float4 q = cb[blk & 2047];

  u32 key[32];
  #pragma unroll
  for (int s = 0; s < 32; ++s) {
    float4 c = cb[s*64 + lane];
    // match reference rounding: inner=((x0y0+x1y1)+x2y2); pd=(2*inner - xn2) - xm2 ; no fma
    float inner = __fadd_rn(__fadd_rn(__fmul_rn(q.x,c.x), __fmul_rn(q.y,c.y)), __fmul_rn(q.z,c.z));
    float pd = __fsub_rn(__fsub_rn(__fmul_rn(2.0f, inner), q.w), c.w);
    u32 bits = __float_as_uint(pd);
    key[s] = (bits & 0x80000000u) ? ~bits : (bits | 0x80000000u);
  }
  // radix-bisect the 80th-largest key value
  u32 T = 0;
  for (int bit = 30; bit >= 0; --bit) {
    u32 Tc = T | (1u << bit);
    int c = 0;
    #pragma unroll
    for (int s = 0; s < 32; ++s) c += (key[s] >= Tc) ? 1 : 0;
    c = wredi(c);
    if (c >= 80) { T = Tc; if (c == 80) break; }
  }
  if (lane == 0) scnt = 0;
  __syncthreads();
  #pragma unroll
  for (int s = 0; s < 32; ++s) {
    if (key[s] >= T) {
      int p = atomicAdd(&scnt, 1);
      if (p < 128) cand[p] = (((u64)key[s]) << 32) | (u32)(2047 - (s*64 + lane));
    }
  }
  __syncthreads();
  int total = scnt; if (total > 128) total = 128;
  for (int i = lane; i < 128; i += 64) if (i >= total) cand[i] = 0ull;
  __syncthreads();
  // bitonic sort 128, descending by (key, then 2047-idx) => ties give smaller idx first
  #pragma unroll
  for (int k2 = 2; k2 <= 128; k2 <<= 1) {
    #pragma unroll
    for (int j = k2 >> 1; j > 0; j >>= 1) {
      int i = ((lane / j) * 2 * j) + (lane % j);
      int p = i + j;
      u64 a = cand[i], c = cand[p];
      bool desc = ((i & k2) == 0);
      if ((a < c) == desc) { cand[i] = c; cand[p] = a; }
      __syncthreads();
    }
  }
  #pragma unroll
  for (int t = lane; t < 80; t += 64) {
    u32 low = (u32)cand[t];
    idxp[blk*80 + t] = 2047 - (int)low;
  }
}

// ---------------- layer 1 conv (K=3, fp32 exact) -> bf16, both a&b paths ----------------
__global__ void k_conv1(const float* __restrict__ x, const float* __restrict__ w1a,
                        const float* __restrict__ w1b, u16* __restrict__ out) {
  int g = blockIdx.x * 256 + threadIdx.x;          // < 16384*128
  int m = g >> 7, o = g & 127;
  const float* w = (o < 64) ? (w1a + 3*o) : (w1b + 3*(o-64));
  const float* xm = x + 3*m;
  float acc = w[0]*xm[0] + w[1]*xm[1] + w[2]*xm[2];
  out[g] = f2bf(acc);
}

// ---------------- GroupNorm stats (one block per (b,group), deterministic) ----------------
__global__ __launch_bounds__(256) void k_stats_bf(const u16* __restrict__ act, int CtotShift,
                                                  int CgShift, int NG, float2* __restrict__ stats) {
  int b = blockIdx.x / NG, g = blockIdx.x % NG;
  int w4s = CgShift - 2;
  int count4 = 2048 << w4s;
  float s = 0.f, ss = 0.f;
  const u16* base = act + (((size_t)(b << 11)) << CtotShift) + ((size_t)g << CgShift);
  for (int i = threadIdx.x; i < count4; i += 256) {
    int n = i >> w4s, cw = i & ((1 << w4s) - 1);
    ushort4 v = *(const ushort4*)(base + (((size_t)n) << CtotShift) + cw*4);
    float a0 = bf2f(v.x), a1 = bf2f(v.y), a2 = bf2f(v.z), a3 = bf2f(v.w);
    s  += a0 + a1 + a2 + a3;
    ss += a0*a0 + a1*a1 + a2*a2 + a3*a3;
  }
  s = wredf(s); ss = wredf(ss);
  __shared__ float red[8];
  int wid = threadIdx.x >> 6;
  if ((threadIdx.x & 63) == 0) { red[wid*2] = s; red[wid*2+1] = ss; }
  __syncthreads();
  if (threadIdx.x == 0) {
    float S = red[0]+red[2]+red[4]+red[6], SS = red[1]+red[3]+red[5]+red[7];
    float cnt = (float)(2048 << CgShift);
    float mean = S / cnt;
    float var = SS / cnt - mean*mean;
    stats[blockIdx.x] = make_float2(mean, rsqrtf(var + 1e-5f));
  }
}

__global__ __launch_bounds__(256) void k_stats_f32(const float* __restrict__ act, int CtotShift,
                                                   int CgShift, int NG, float2* __restrict__ stats) {
  int b = blockIdx.x / NG, g = blockIdx.x % NG;
  int w4s = CgShift - 2;
  int count4 = 2048 << w4s;
  float s = 0.f, ss = 0.f;
  const float* base = act + (((size_t)(b << 11)) << CtotShift) + ((size_t)g << CgShift);
  for (int i = threadIdx.x; i < count4; i += 256) {
    int n = i >> w4s, cw = i & ((1 << w4s) - 1);
    float4 v = *(const float4*)(base + (((size_t)n) << CtotShift) + cw*4);
    s  += v.x + v.y + v.z + v.w;
    ss += v.x*v.x + v.y*v.y + v.z*v.z + v.w*v.w;
  }
  s = wredf(s); ss = wredf(ss);
  __shared__ float red[8];
  int wid = threadIdx.x >> 6;
  if ((threadIdx.x & 63) == 0) { red[wid*2] = s; red[wid*2+1] = ss; }
  __syncthreads();
  if (threadIdx.x == 0) {
    float S = red[0]+red[2]+red[4]+red[6], SS = red[1]+red[3]+red[5]+red[7];
    float cnt = (float)(2048 << CgShift);
    float mean = S / cnt;
    float var = SS / cnt - mean*mean;
    stats[blockIdx.x] = make_float2(mean, rsqrtf(var + 1e-5f));
  }
}

// ---------------- GN apply + LeakyReLU, in place (bf16), split gamma/beta a|b ----------------
__global__ __launch_bounds__(256) void k_apply_bf(u16* __restrict__ act, int CtotShift, int CgShift,
    int NG, const float2* __restrict__ stats, const float* __restrict__ ga, const float* __restrict__ ba,
    const float* __restrict__ gb, const float* __restrict__ bb, int Ca) {
  int gid = blockIdx.x * 256 + threadIdx.x;
  size_t e = (size_t)gid * 8;
  int Ctot = 1 << CtotShift;
  int row = (int)(e >> CtotShift);
  int c = (int)e & (Ctot - 1);
  int g = c >> CgShift;
  float2 st = stats[(row >> 11) * NG + g];
  uint4 v = *(const uint4*)(act + e);
  u32 vv[4] = {v.x, v.y, v.z, v.w};
  #pragma unroll
  for (int q2 = 0; q2 < 4; ++q2) {
    int c0 = c + q2*2, c1 = c0 + 1;
    float x0 = bf2f((u16)(vv[q2] & 0xFFFF));
    float x1 = bf2f((u16)(vv[q2] >> 16));
    float G0 = (c0 < Ca) ? ga[c0] : gb[c0 - Ca];
    float B0 = (c0 < Ca) ? ba[c0] : bb[c0 - Ca];
    float G1 = (c1 < Ca) ? ga[c1] : gb[c1 - Ca];
    float B1 = (c1 < Ca) ? ba[c1] : bb[c1 - Ca];
    float h0 = (x0 - st.x) * st.y * G0 + B0;
    float h1 = (x1 - st.x) * st.y * G1 + B1;
    h0 = h0 > 0.f ? h0 : 0.2f * h0;
    h1 = h1 > 0.f ? h1 : 0.2f * h1;
    vv[q2] = (u32)f2bf(h0) | (((u32)f2bf(h1)) << 16);
  }
  *(uint4*)(act + e) = make_uint4(vv[0], vv[1], vv[2], vv[3]);
}

__global__ __launch_bounds__(256) void k_apply_f32(float* __restrict__ act, int NG, int CgShift,
    const float2* __restrict__ stats, const float* __restrict__ ga, const float* __restrict__ ba) {
  int gid = blockIdx.x * 256 + threadIdx.x;
  size_t e = (size_t)gid * 4;
  int row = (int)(e >> 9);               // Ctot = 512
  int c = (int)e & 511;
  int g = c >> CgShift;
  float2 st = stats[(row >> 11) * NG + g];
  float4 v = *(const float4*)(act + e);
  float h[4] = {v.x, v.y, v.z, v.w};
  #pragma unroll
  for (int q = 0; q < 4; ++q) {
    float xn = (h[q] - st.x) * st.y;
    float o = xn * ga[c+q] + ba[c+q];
    h[q] = o > 0.f ? o : 0.2f * o;
  }
  *(float4*)(act + e) = make_float4(h[0], h[1], h[2], h[3]);
}

// ---------------- gather-max over k neighbors + add fb -> xcat slice ----------------
// Batch->XCD pinned: batch = blockIdx.x & 7 so each XCD's L2 holds exactly one
// batch's activation table (<= 2 MB). 16B row loads, int4 index loads.
__global__ __launch_bounds__(256) void k_gather(const u16* __restrict__ conv, int Ctot, int Ca,
    const int* __restrict__ idxp, int k, u16* __restrict__ xcat, int outOff, int lppShift) {
  const int batch = blockIdx.x & 7;
  const int blkin = blockIdx.x >> 3;
  const int lgid = blkin * 256 + threadIdx.x;        // within batch
  const int p_in = lgid >> lppShift;                 // point within batch, < 2048
  const int c8 = (lgid & ((1 << lppShift) - 1)) * 8; // channel offset (8 bf16 per lane)
  const int p = (batch << 11) + p_in;
  const int* irow = idxp + (size_t)p * 80;
  const u16* cb = conv + ((size_t)(batch << 11)) * Ctot + c8;

  // fb read issued early (independent of gather chain)
  uint4 fbv = *(const uint4*)(conv + (size_t)p * Ctot + Ca + c8);

  float m[8];
  #pragma unroll
  for (int q = 0; q < 8; ++q) m[q] = -3.4e38f;

  for (int j0 = 0; j0 < k; j0 += 4) {
    int4 mi4 = *(const int4*)(irow + j0);
    int mis[4] = {mi4.x, mi4.y, mi4.z, mi4.w};
    uint4 rows[4];
    #pragma unroll
    for (int u = 0; u < 4; ++u)
      rows[u] = *(const uint4*)(cb + (size_t)mis[u] * Ctot);
    #pragma unroll
    for (int u = 0; u < 4; ++u) {
      u32 rv[4] = {rows[u].x, rows[u].y, rows[u].z, rows[u].w};
      #pragma unroll
      for (int q2 = 0; q2 < 4; ++q2) {
        m[q2*2]   = fmaxf(m[q2*2],   bf2f((u16)(rv[q2] & 0xFFFF)));
        m[q2*2+1] = fmaxf(m[q2*2+1], bf2f((u16)(rv[q2] >> 16)));
      }
    }
  }
  u32 fv[4] = {fbv.x, fbv.y, fbv.z, fbv.w};
  u32 ov[4];
  #pragma unroll
  for (int q2 = 0; q2 < 4; ++q2) {
    float o0 = m[q2*2]   + bf2f((u16)(fv[q2] & 0xFFFF));
    float o1 = m[q2*2+1] + bf2f((u16)(fv[q2] >> 16));
    ov[q2] = (u32)f2bf(o0) | (((u32)f2bf(o1)) << 16);
  }
  *(uint4*)(xcat + (size_t)p * 512 + outOff + c8) = make_uint4(ov[0], ov[1], ov[2], ov[3]);
}

// ---------------- bf16 MFMA GEMM: C[M x N] = A[M x K] * W[N x K]^T ----------------
template<int OUTF32>
__global__ __launch_bounds__(256) void k_gemm(const u16* __restrict__ A, int lda,
    const u16* __restrict__ Bw, int K, void* __restrict__ outp, int ldc) {
  constexpr int BK = 64;
  __shared__ __align__(16) u16 As[128 * BK];
  __shared__ __align__(16) u16 Bs[128 * BK];
  const int tid = threadIdx.x;
  const int wid = tid >> 6, lane = tid & 63;
  const int tileM = blockIdx.x * 128, tileN = blockIdx.y * 128;
  const int wm = wid >> 1, wn = wid & 1;           // 2x2 waves, 64x64 each
  const int lr = lane & 15, lk = (lane >> 4) * 8;
  f32x4 acc[4][4] = {};
  for (int k0 = 0; k0 < K; k0 += BK) {
    __syncthreads();
    #pragma unroll
    for (int i = 0; i < 4; ++i) {
      int flat = i * 256 + tid;
      int row = flat >> 3, ck = flat & 7;
      glds16(A + (size_t)(tileM + row) * lda + (k0 + ck * 8), (char*)As + flat * 16);
    }
    #pragma unroll
    for (int i = 0; i < 4; ++i) {
      int flat = i * 256 + tid;
      int row = flat >> 3, ck = flat & 7;
      glds16(Bw + (size_t)(tileN + row) * K + (k0 + ck * 8), (char*)Bs + flat * 16);
    }
    __syncthreads();                                // drains vmcnt before barrier
    #pragma unroll
    for (int ks = 0; ks < 2; ++ks) {
      bf16x8 af[4], bfr[4];
      #pragma unroll
      for (int i = 0; i < 4; ++i)
        af[i] = *(const bf16x8*)&As[(wm*64 + i*16 + lr) * BK + ks*32 + lk];
      #pragma unroll
      for (int j = 0; j < 4; ++j)
        bfr[j] = *(const bf16x8*)&Bs[(wn*64 + j*16 + lr) * BK + ks*32 + lk];
      #pragma unroll
      for (int i = 0; i < 4; ++i)
        #pragma unroll
        for (int j = 0; j < 4; ++j)
          acc[i][j] = __builtin_amdgcn_mfma_f32_16x16x32_bf16(af[i], bfr[j], acc[i][j], 0, 0, 0);
    }
  }
  const int orow0 = tileM + wm*64 + ((lane >> 4) * 4);
  const int ocol0 = tileN + wn*64 + lr;
  #pragma unroll
  for (int i = 0; i < 4; ++i)
    #pragma unroll
    for (int j = 0; j < 4; ++j)
      #pragma unroll
      for (int r = 0; r < 4; ++r) {
        int row = orow0 + i*16 + r;
        int col = ocol0 + j*16;
        float v = acc[i][j][r];
        if (OUTF32) ((float*)outp)[(size_t)row * ldc + col] = v;
        else        ((u16*)outp)[(size_t)row * ldc + col] = f2bf(v);
      }
}

// ---------------- launch ----------------
extern "C" void kernel_launch(void* const* d_in, const int* in_sizes, int n_in,
                              void* d_out, int out_size, void* d_ws, size_t ws_size,
                              hipStream_t stream) {
  const float* x   = (const float*)d_in[0];
  const float* w1a = (const float*)d_in[1];
  const float* g1a = (const float*)d_in[2];
  const float* b1a = (const float*)d_in[3];
  const float* w1b = (const float*)d_in[4];
  const float* g1b = (const float*)d_in[5];
  const float* b1b = (const float*)d_in[6];
  const float* w2a = (const float*)d_in[7];
  const float* g2a = (const float*)d_in[8];
  const float* b2a = (const float*)d_in[9];
  const float* w2b = (const float*)d_in[10];
  const float* g2b = (const float*)d_in[11];
  const float* b2b = (const float*)d_in[12];
  const float* w3a = (const float*)d_in[13];
  const float* g3a = (const float*)d_in[14];
  const float* b3a = (const float*)d_in[15];
  const float* w3b = (const float*)d_in[16];
  const float* g3b = (const float*)d_in[17];
  const float* b3b = (const float*)d_in[18];
  const float* w4a = (const float*)d_in[19];
  const float* g4a = (const float*)d_in[20];
  const float* b4a = (const float*)d_in[21];
  const float* w4b = (const float*)d_in[22];
  const float* g4b = (const float*)d_in[23];
  const float* b4b = (const float*)d_in[24];
  const float* w51 = (const float*)d_in[25];
  const float* g51 = (const float*)d_in[26];
  const float* b51 = (const float*)d_in[27];
  const float* w52 = (const float*)d_in[28];
  const float* g52 = (const float*)d_in[29];
  const float* b52 = (const float*)d_in[30];

  char* ws = (char*)d_ws;                           // ~75 MB used
  int*    idxp   = (int*)   (ws + 0);               // 16384*80*4   = 5,242,880
  float4* c4     = (float4*)(ws + 5242880);         // 16384*16     = 262,144
  u16*    wbf    = (u16*)   (ws + 5505024);         // 1,138,688*2  = 2,277,376
  float2* stats  = (float2*)(ws + 7782400);         // 256*8        = 2,048
  u16*    convAB = (u16*)   (ws + 7784448);         // 16 MB
  u16*    h1     = (u16*)   (ws + 24561664);        // 32 MB
  u16*    xcat   = (u16*)   (ws + 58116096);        // 16 MB
  u16* wc2 = wbf, *wc3 = wbf + 8192, *wc4 = wbf + 24576;
  u16* w51b = wbf + 90112, *w52b = wbf + 614400;
  float* outf = (float*)d_out;

  k_pack_coords<<<64, 256, 0, stream>>>(x, c4);
  k_pack_w<<<4448, 256, 0, stream>>>(w2a, w2b, w3a, w3b, w4a, w4b, w51, w52, wbf);
  k_knn<<<16384, 64, 0, stream>>>(c4, idxp);

  // layer 1 (3->64 x2, groups 8 each => combined 16 groups of 8)
  k_conv1<<<8192, 256, 0, stream>>>(x, w1a, w1b, convAB);
  k_stats_bf<<<128, 256, 0, stream>>>(convAB, 7, 3, 16, stats);
  k_apply_bf<<<1024, 256, 0, stream>>>(convAB, 7, 3, 16, stats, g1a, b1a, g1b, b1b, 64);
  k_gather<<<512, 256, 0, stream>>>(convAB, 128, 64, idxp, 20, xcat, 0, 3);

  // layer 2 (64->64 x2)
  k_gemm<0><<<dim3(128,1), 256, 0, stream>>>(xcat + 0, 512, wc2, 64, convAB, 128);
  k_stats_bf<<<128, 256, 0, stream>>>(convAB, 7, 3, 16, stats);
  k_apply_bf<<<1024, 256, 0, stream>>>(convAB, 7, 3, 16, stats, g2a, b2a, g2b, b2b, 64);
  k_gather<<<512, 256, 0, stream>>>(convAB, 128, 64, idxp, 40, xcat, 64, 3);

  // layer 3 (64->128 x2, groups 8 => Cg 16, combined 16 groups)
  k_gemm<0><<<dim3(128,2), 256, 0, stream>>>(xcat + 64, 512, wc3, 64, convAB, 256);
  k_stats_bf<<<128, 256, 0, stream>>>(convAB, 8, 4, 16, stats);
  k_apply_bf<<<2048, 256, 0, stream>>>(convAB, 8, 4, 16, stats, g3a, b3a, g3b, b3b, 128);
  k_gather<<<1024, 256, 0, stream>>>(convAB, 256, 128, idxp, 60, xcat, 128, 4);

  // layer 4 (128->256 x2, groups 16 => Cg 16, combined 32 groups)
  k_gemm<0><<<dim3(128,4), 256, 0, stream>>>(xcat + 128, 512, wc4, 128, convAB, 512);
  k_stats_bf<<<256, 256, 0, stream>>>(convAB, 9, 4, 32, stats);
  k_apply_bf<<<4096, 256, 0, stream>>>(convAB, 9, 4, 32, stats, g4a, b4a, g4b, b4b, 256);
  k_gather<<<2048, 256, 0, stream>>>(convAB, 512, 256, idxp, 80, xcat, 256, 5);

  // layer 5_1 (512->1024, groups 16 => Cg 64)
  k_gemm<0><<<dim3(128,8), 256, 0, stream>>>(xcat, 512, w51b, 512, h1, 1024);
  k_stats_bf<<<128, 256, 0, stream>>>(h1, 10, 6, 16, stats);
  k_apply_bf<<<8192, 256, 0, stream>>>(h1, 10, 6, 16, stats, g51, b51, g51, b51, 1024);

  // layer 5_2 (1024->512, groups 16 => Cg 32), fp32 out in d_out, GN+LReLU in place
  k_gemm<1><<<dim3(128,4), 256, 0, stream>>>(h1, 1024, w52b, 1024, (void*)outf, 512);
  k_stats_f32<<<128, 256, 0, stream>>>(outf, 9, 5, 16, stats);
  k_apply_f32<<<8192, 256, 0, stream>>>(outf, 16, 5, stats, g52, b52);
}

// Round 3
// 501.789 us; speedup vs baseline: 1.2639x; 1.0428x over previous
//
#include <hip/hip_runtime.h>
#include <stdint.h>

typedef unsigned short u16;
typedef unsigned int u32;
typedef unsigned long long u64;
typedef __attribute__((ext_vector_type(8))) __bf16 bf16x8;
typedef __attribute__((ext_vector_type(4))) float f32x4;

#define DEVI __device__ __forceinline__

DEVI u16 f2bf(float f) {                    // fp32 -> bf16 RNE
  u32 u = __float_as_uint(f);
  u += 0x7FFFu + ((u >> 16) & 1u);
  return (u16)(u >> 16);
}
DEVI float bf2f(u16 h) { return __uint_as_float(((u32)h) << 16); }

DEVI float wredf(float v) {
  #pragma unroll
  for (int m = 32; m; m >>= 1) v += __shfl_xor(v, m, 64);
  return v;
}

DEVI void glds16(const void* g, void* l) {  // 16B-per-lane global->LDS DMA
  __builtin_amdgcn_global_load_lds((const __attribute__((address_space(1))) void*)g,
                                   (__attribute__((address_space(3))) void*)l, 16, 0, 0);
}

// ---------------- prep: pack (x,y,z,||x||^2) per point ----------------
__global__ void k_pack_coords(const float* __restrict__ x, float4* __restrict__ c4) {
  int g = blockIdx.x * 256 + threadIdx.x;          // < 16384
  float x0 = x[g*3], x1 = x[g*3+1], x2 = x[g*3+2];
  float n = __fadd_rn(__fadd_rn(__fmul_rn(x0,x0), __fmul_rn(x1,x1)), __fmul_rn(x2,x2));
  c4[g] = make_float4(x0, x1, x2, n);
}

// ---------------- prep: all MFMA weights -> bf16 (a/b stacked) ----------------
__global__ void k_pack_w(const float* __restrict__ w2a, const float* __restrict__ w2b,
                         const float* __restrict__ w3a, const float* __restrict__ w3b,
                         const float* __restrict__ w4a, const float* __restrict__ w4b,
                         const float* __restrict__ w51, const float* __restrict__ w52,
                         u16* __restrict__ wbf) {
  int g = blockIdx.x * 256 + threadIdx.x;          // < 1,138,688 exact
  const float* s; int off;
  if      (g <    4096) { s = w2a; off = g; }
  else if (g <    8192) { s = w2b; off = g - 4096; }
  else if (g <   16384) { s = w3a; off = g - 8192; }
  else if (g <   24576) { s = w3b; off = g - 16384; }
  else if (g <   57344) { s = w4a; off = g - 24576; }
  else if (g <   90112) { s = w4b; off = g - 57344; }
  else if (g <  614400) { s = w51; off = g - 90112; }
  else                  { s = w52; off = g - 614400; }
  wbf[g] = f2bf(s[off]);
}

// ---------------- knn: per-row top-80 (sorted desc, ties by low index) ----------------
// 4 query-waves per block. Ballot-count radix bisect with [80,128] early break;
// candidate compaction via ballot-prefix (no atomics); 128-elem bitonic sort
// fully in registers via shfl_xor (2 elems/lane, u64 keys).
__global__ __launch_bounds__(256) void k_knn(const float4* __restrict__ c4, int* __restrict__ idxp) {
  __shared__ u64 cand[4][128];
  const int wid = threadIdx.x >> 6;
  const int lane = threadIdx.x & 63;
  const int blk = blockIdx.x * 4 + wid;             // query id = b*2048 + n
  const int b = blk >> 11;
  const float4* cb = c4 + (b << 11);
  const float4 q = cb[blk & 2047];

  u32 key[32];
  #pragma unroll
  for (int s = 0; s < 32; ++s) {
    float4 c = cb[s*64 + lane];
    // match reference rounding: inner=((x0y0+x1y1)+x2y2); pd=(2*inner - xn2) - xm2 ; no fma
    float inner = __fadd_rn(__fadd_rn(__fmul_rn(q.x,c.x), __fmul_rn(q.y,c.y)), __fmul_rn(q.z,c.z));
    float pd = __fsub_rn(__fsub_rn(__fmul_rn(2.0f, inner), q.w), c.w);
    u32 bits = __float_as_uint(pd);
    key[s] = (bits & 0x80000000u) ? ~bits : (bits | 0x80000000u);
  }

  // radix-bisect: find T with 80 <= count(key >= T) <= 128 (early break),
  // else exact-80 refinement continues to bit 0.
  u32 T = 0;
  for (int bit = 30; bit >= 0; --bit) {
    u32 Tc = T | (1u << bit);
    int c = 0;
    #pragma unroll
    for (int s = 0; s < 32; ++s)
      c += __popcll(__ballot(key[s] >= Tc));
    if (c >= 80) { T = Tc; if (c <= 128) break; }
  }

  // zero-fill candidate buffer
  cand[wid][lane] = 0ull;
  cand[wid][lane + 64] = 0ull;
  __syncthreads();

  // compact survivors: unique positions via ballot prefix (deterministic)
  const u64 below = (lane == 0) ? 0ull : (~0ull >> (64 - lane));
  int base = 0;
  #pragma unroll
  for (int s = 0; s < 32; ++s) {
    u64 msk = __ballot(key[s] >= T);
    if (key[s] >= T) {
      int pos = base + (int)__popcll(msk & below);
      if (pos < 128)
        cand[wid][pos] = (((u64)key[s]) << 32) | (u32)(2047 - (s*64 + lane));
    }
    base += (int)__popcll(msk);
  }
  __syncthreads();

  // register bitonic sort of 128 (descending): slot0 = elem[lane], slot1 = elem[lane+64]
  u64 v0 = cand[wid][lane];
  u64 v1 = cand[wid][lane + 64];
  #pragma unroll
  for (int k2 = 2; k2 <= 128; k2 <<= 1) {
    #pragma unroll
    for (int j = k2 >> 1; j > 0; j >>= 1) {
      if (j == 64) {                                // cross-slot, in-lane (k2==128 only)
        u64 mx = v0 > v1 ? v0 : v1;
        u64 mn = v0 > v1 ? v1 : v0;
        v0 = mx; v1 = mn;                           // desc=((lane&128)==0)=true -> low keeps max
      } else {
        u64 p0 = __shfl_xor(v0, j, 64);
        u64 p1 = __shfl_xor(v1, j, 64);
        bool lowlane = ((lane & j) == 0);
        bool d0 = ((lane & k2) == 0);               // elem index = lane
        bool d1 = (((lane + 64) & k2) == 0);        // elem index = lane+64
        bool wm0 = (d0 == lowlane);
        bool wm1 = (d1 == lowlane);
        u64 mx0 = v0 > p0 ? v0 : p0, mn0 = v0 > p0 ? p0 : v0;
        u64 mx1 = v1 > p1 ? v1 : p1, mn1 = v1 > p1 ? p1 : v1;
        v0 = wm0 ? mx0 : mn0;
        v1 = wm1 ? mx1 : mn1;
      }
    }
  }

  // ranks: elem[lane]=rank lane (v0), elem[64+lane]=rank 64+lane (v1); emit top 80
  idxp[blk*80 + lane] = 2047 - (int)(u32)v0;
  if (lane < 16) idxp[blk*80 + 64 + lane] = 2047 - (int)(u32)v1;
}

// ---------------- layer 1 conv (K=3, fp32 exact) -> bf16, both a&b paths ----------------
__global__ void k_conv1(const float* __restrict__ x, const float* __restrict__ w1a,
                        const float* __restrict__ w1b, u16* __restrict__ out) {
  int g = blockIdx.x * 256 + threadIdx.x;          // < 16384*128
  int m = g >> 7, o = g & 127;
  const float* w = (o < 64) ? (w1a + 3*o) : (w1b + 3*(o-64));
  const float* xm = x + 3*m;
  float acc = w[0]*xm[0] + w[1]*xm[1] + w[2]*xm[2];
  out[g] = f2bf(acc);
}

// ---------------- GroupNorm stats (one block per (b,group), deterministic) ----------------
__global__ __launch_bounds__(256) void k_stats_bf(const u16* __restrict__ act, int CtotShift,
                                                  int CgShift, int NG, float2* __restrict__ stats) {
  int b = blockIdx.x / NG, g = blockIdx.x % NG;
  int w4s = CgShift - 2;
  int count4 = 2048 << w4s;
  float s = 0.f, ss = 0.f;
  const u16* base = act + (((size_t)(b << 11)) << CtotShift) + ((size_t)g << CgShift);
  for (int i = threadIdx.x; i < count4; i += 256) {
    int n = i >> w4s, cw = i & ((1 << w4s) - 1);
    ushort4 v = *(const ushort4*)(base + (((size_t)n) << CtotShift) + cw*4);
    float a0 = bf2f(v.x), a1 = bf2f(v.y), a2 = bf2f(v.z), a3 = bf2f(v.w);
    s  += a0 + a1 + a2 + a3;
    ss += a0*a0 + a1*a1 + a2*a2 + a3*a3;
  }
  s = wredf(s); ss = wredf(ss);
  __shared__ float red[8];
  int wid = threadIdx.x >> 6;
  if ((threadIdx.x & 63) == 0) { red[wid*2] = s; red[wid*2+1] = ss; }
  __syncthreads();
  if (threadIdx.x == 0) {
    float S = red[0]+red[2]+red[4]+red[6], SS = red[1]+red[3]+red[5]+red[7];
    float cnt = (float)(2048 << CgShift);
    float mean = S / cnt;
    float var = SS / cnt - mean*mean;
    stats[blockIdx.x] = make_float2(mean, rsqrtf(var + 1e-5f));
  }
}

__global__ __launch_bounds__(256) void k_stats_f32(const float* __restrict__ act, int CtotShift,
                                                   int CgShift, int NG, float2* __restrict__ stats) {
  int b = blockIdx.x / NG, g = blockIdx.x % NG;
  int w4s = CgShift - 2;
  int count4 = 2048 << w4s;
  float s = 0.f, ss = 0.f;
  const float* base = act + (((size_t)(b << 11)) << CtotShift) + ((size_t)g << CgShift);
  for (int i = threadIdx.x; i < count4; i += 256) {
    int n = i >> w4s, cw = i & ((1 << w4s) - 1);
    float4 v = *(const float4*)(base + (((size_t)n) << CtotShift) + cw*4);
    s  += v.x + v.y + v.z + v.w;
    ss += v.x*v.x + v.y*v.y + v.z*v.z + v.w*v.w;
  }
  s = wredf(s); ss = wredf(ss);
  __shared__ float red[8];
  int wid = threadIdx.x >> 6;
  if ((threadIdx.x & 63) == 0) { red[wid*2] = s; red[wid*2+1] = ss; }
  __syncthreads();
  if (threadIdx.x == 0) {
    float S = red[0]+red[2]+red[4]+red[6], SS = red[1]+red[3]+red[5]+red[7];
    float cnt = (float)(2048 << CgShift);
    float mean = S / cnt;
    float var = SS / cnt - mean*mean;
    stats[blockIdx.x] = make_float2(mean, rsqrtf(var + 1e-5f));
  }
}

// ---------------- GN apply + LeakyReLU, in place (bf16), split gamma/beta a|b ----------------
__global__ __launch_bounds__(256) void k_apply_bf(u16* __restrict__ act, int CtotShift, int CgShift,
    int NG, const float2* __restrict__ stats, const float* __restrict__ ga, const float* __restrict__ ba,
    const float* __restrict__ gb, const float* __restrict__ bb, int Ca) {
  int gid = blockIdx.x * 256 + threadIdx.x;
  size_t e = (size_t)gid * 8;
  int Ctot = 1 << CtotShift;
  int row = (int)(e >> CtotShift);
  int c = (int)e & (Ctot - 1);
  int g = c >> CgShift;
  float2 st = stats[(row >> 11) * NG + g];
  uint4 v = *(const uint4*)(act + e);
  u32 vv[4] = {v.x, v.y, v.z, v.w};
  #pragma unroll
  for (int q2 = 0; q2 < 4; ++q2) {
    int c0 = c + q2*2, c1 = c0 + 1;
    float x0 = bf2f((u16)(vv[q2] & 0xFFFF));
    float x1 = bf2f((u16)(vv[q2] >> 16));
    float G0 = (c0 < Ca) ? ga[c0] : gb[c0 - Ca];
    float B0 = (c0 < Ca) ? ba[c0] : bb[c0 - Ca];
    float G1 = (c1 < Ca) ? ga[c1] : gb[c1 - Ca];
    float B1 = (c1 < Ca) ? ba[c1] : bb[c1 - Ca];
    float h0 = (x0 - st.x) * st.y * G0 + B0;
    float h1 = (x1 - st.x) * st.y * G1 + B1;
    h0 = h0 > 0.f ? h0 : 0.2f * h0;
    h1 = h1 > 0.f ? h1 : 0.2f * h1;
    vv[q2] = (u32)f2bf(h0) | (((u32)f2bf(h1)) << 16);
  }
  *(uint4*)(act + e) = make_uint4(vv[0], vv[1], vv[2], vv[3]);
}

__global__ __launch_bounds__(256) void k_apply_f32(float* __restrict__ act, int NG, int CgShift,
    const float2* __restrict__ stats, const float* __restrict__ ga, const float* __restrict__ ba) {
  int gid = blockIdx.x * 256 + threadIdx.x;
  size_t e = (size_t)gid * 4;
  int row = (int)(e >> 9);               // Ctot = 512
  int c = (int)e & 511;
  int g = c >> CgShift;
  float2 st = stats[(row >> 11) * NG + g];
  float4 v = *(const float4*)(act + e);
  float h[4] = {v.x, v.y, v.z, v.w};
  #pragma unroll
  for (int q = 0; q < 4; ++q) {
    float xn = (h[q] - st.x) * st.y;
    float o = xn * ga[c+q] + ba[c+q];
    h[q] = o > 0.f ? o : 0.2f * o;
  }
  *(float4*)(act + e) = make_float4(h[0], h[1], h[2], h[3]);
}

// ---------------- gather-max over k neighbors + add fb -> xcat slice ----------------
// Batch->XCD pinned: batch = blockIdx.x & 7 so each XCD's L2 holds exactly one
// batch's activation table (<= 2 MB). 16B row loads, int4 index loads.
__global__ __launch_bounds__(256) void k_gather(const u16* __restrict__ conv, int Ctot, int Ca,
    const int* __restrict__ idxp, int k, u16* __restrict__ xcat, int outOff, int lppShift) {
  const int batch = blockIdx.x & 7;
  const int blkin = blockIdx.x >> 3;
  const int lgid = blkin * 256 + threadIdx.x;        // within batch
  const int p_in = lgid >> lppShift;                 // point within batch, < 2048
  const int c8 = (lgid & ((1 << lppShift) - 1)) * 8; // channel offset (8 bf16 per lane)
  const int p = (batch << 11) + p_in;
  const int* irow = idxp + (size_t)p * 80;
  const u16* cb = conv + ((size_t)(batch << 11)) * Ctot + c8;

  // fb read issued early (independent of gather chain)
  uint4 fbv = *(const uint4*)(conv + (size_t)p * Ctot + Ca + c8);

  float m[8];
  #pragma unroll
  for (int q = 0; q < 8; ++q) m[q] = -3.4e38f;

  for (int j0 = 0; j0 < k; j0 += 4) {
    int4 mi4 = *(const int4*)(irow + j0);
    int mis[4] = {mi4.x, mi4.y, mi4.z, mi4.w};
    uint4 rows[4];
    #pragma unroll
    for (int u = 0; u < 4; ++u)
      rows[u] = *(const uint4*)(cb + (size_t)mis[u] * Ctot);
    #pragma unroll
    for (int u = 0; u < 4; ++u) {
      u32 rv[4] = {rows[u].x, rows[u].y, rows[u].z, rows[u].w};
      #pragma unroll
      for (int q2 = 0; q2 < 4; ++q2) {
        m[q2*2]   = fmaxf(m[q2*2],   bf2f((u16)(rv[q2] & 0xFFFF)));
        m[q2*2+1] = fmaxf(m[q2*2+1], bf2f((u16)(rv[q2] >> 16)));
      }
    }
  }
  u32 fv[4] = {fbv.x, fbv.y, fbv.z, fbv.w};
  u32 ov[4];
  #pragma unroll
  for (int q2 = 0; q2 < 4; ++q2) {
    float o0 = m[q2*2]   + bf2f((u16)(fv[q2] & 0xFFFF));
    float o1 = m[q2*2+1] + bf2f((u16)(fv[q2] >> 16));
    ov[q2] = (u32)f2bf(o0) | (((u32)f2bf(o1)) << 16);
  }
  *(uint4*)(xcat + (size_t)p * 512 + outOff + c8) = make_uint4(ov[0], ov[1], ov[2], ov[3]);
}

// ---------------- bf16 MFMA GEMM: C[M x N] = A[M x K] * W[N x K]^T ----------------
template<int OUTF32>
__global__ __launch_bounds__(256) void k_gemm(const u16* __restrict__ A, int lda,
    const u16* __restrict__ Bw, int K, void* __restrict__ outp, int ldc) {
  constexpr int BK = 64;
  __shared__ __align__(16) u16 As[128 * BK];
  __shared__ __align__(16) u16 Bs[128 * BK];
  const int tid = threadIdx.x;
  const int wid = tid >> 6, lane = tid & 63;
  const int tileM = blockIdx.x * 128, tileN = blockIdx.y * 128;
  const int wm = wid >> 1, wn = wid & 1;           // 2x2 waves, 64x64 each
  const int lr = lane & 15, lk = (lane >> 4) * 8;
  f32x4 acc[4][4] = {};
  for (int k0 = 0; k0 < K; k0 += BK) {
    __syncthreads();
    #pragma unroll
    for (int i = 0; i < 4; ++i) {
      int flat = i * 256 + tid;
      int row = flat >> 3, ck = flat & 7;
      glds16(A + (size_t)(tileM + row) * lda + (k0 + ck * 8), (char*)As + flat * 16);
    }
    #pragma unroll
    for (int i = 0; i < 4; ++i) {
      int flat = i * 256 + tid;
      int row = flat >> 3, ck = flat & 7;
      glds16(Bw + (size_t)(tileN + row) * K + (k0 + ck * 8), (char*)Bs + flat * 16);
    }
    __syncthreads();                                // drains vmcnt before barrier
    #pragma unroll
    for (int ks = 0; ks < 2; ++ks) {
      bf16x8 af[4], bfr[4];
      #pragma unroll
      for (int i = 0; i < 4; ++i)
        af[i] = *(const bf16x8*)&As[(wm*64 + i*16 + lr) * BK + ks*32 + lk];
      #pragma unroll
      for (int j = 0; j < 4; ++j)
        bfr[j] = *(const bf16x8*)&Bs[(wn*64 + j*16 + lr) * BK + ks*32 + lk];
      #pragma unroll
      for (int i = 0; i < 4; ++i)
        #pragma unroll
        for (int j = 0; j < 4; ++j)
          acc[i][j] = __builtin_amdgcn_mfma_f32_16x16x32_bf16(af[i], bfr[j], acc[i][j], 0, 0, 0);
    }
  }
  const int orow0 = tileM + wm*64 + ((lane >> 4) * 4);
  const int ocol0 = tileN + wn*64 + lr;
  #pragma unroll
  for (int i = 0; i < 4; ++i)
    #pragma unroll
    for (int j = 0; j < 4; ++j)
      #pragma unroll
      for (int r = 0; r < 4; ++r) {
        int row = orow0 + i*16 + r;
        int col = ocol0 + j*16;
        float v = acc[i][j][r];
        if (OUTF32) ((float*)outp)[(size_t)row * ldc + col] = v;
        else        ((u16*)outp)[(size_t)row * ldc + col] = f2bf(v);
      }
}

// ---------------- launch ----------------
extern "C" void kernel_launch(void* const* d_in, const int* in_sizes, int n_in,
                              void* d_out, int out_size, void* d_ws, size_t ws_size,
                              hipStream_t stream) {
  const float* x   = (const float*)d_in[0];
  const float* w1a = (const float*)d_in[1];
  const float* g1a = (const float*)d_in[2];
  const float* b1a = (const float*)d_in[3];
  const float* w1b = (const float*)d_in[4];
  const float* g1b = (const float*)d_in[5];
  const float* b1b = (const float*)d_in[6];
  const float* w2a = (const float*)d_in[7];
  const float* g2a = (const float*)d_in[8];
  const float* b2a = (const float*)d_in[9];
  const float* w2b = (const float*)d_in[10];
  const float* g2b = (const float*)d_in[11];
  const float* b2b = (const float*)d_in[12];
  const float* w3a = (const float*)d_in[13];
  const float* g3a = (const float*)d_in[14];
  const float* b3a = (const float*)d_in[15];
  const float* w3b = (const float*)d_in[16];
  const float* g3b = (const float*)d_in[17];
  const float* b3b = (const float*)d_in[18];
  const float* w4a = (const float*)d_in[19];
  const float* g4a = (const float*)d_in[20];
  const float* b4a = (const float*)d_in[21];
  const float* w4b = (const float*)d_in[22];
  const float* g4b = (const float*)d_in[23];
  const float* b4b = (const float*)d_in[24];
  const float* w51 = (const float*)d_in[25];
  const float* g51 = (const float*)d_in[26];
  const float* b51 = (const float*)d_in[27];
  const float* w52 = (const float*)d_in[28];
  const float* g52 = (const float*)d_in[29];
  const float* b52 = (const float*)d_in[30];

  char* ws = (char*)d_ws;                           // ~75 MB used
  int*    idxp   = (int*)   (ws + 0);               // 16384*80*4   = 5,242,880
  float4* c4     = (float4*)(ws + 5242880);         // 16384*16     = 262,144
  u16*    wbf    = (u16*)   (ws + 5505024);         // 1,138,688*2  = 2,277,376
  float2* stats  = (float2*)(ws + 7782400);         // 256*8        = 2,048
  u16*    convAB = (u16*)   (ws + 7784448);         // 16 MB
  u16*    h1     = (u16*)   (ws + 24561664);        // 32 MB
  u16*    xcat   = (u16*)   (ws + 58116096);        // 16 MB
  u16* wc2 = wbf, *wc3 = wbf + 8192, *wc4 = wbf + 24576;
  u16* w51b = wbf + 90112, *w52b = wbf + 614400;
  float* outf = (float*)d_out;

  k_pack_coords<<<64, 256, 0, stream>>>(x, c4);
  k_pack_w<<<4448, 256, 0, stream>>>(w2a, w2b, w3a, w3b, w4a, w4b, w51, w52, wbf);
  k_knn<<<4096, 256, 0, stream>>>(c4, idxp);

  // layer 1 (3->64 x2, groups 8 each => combined 16 groups of 8)
  k_conv1<<<8192, 256, 0, stream>>>(x, w1a, w1b, convAB);
  k_stats_bf<<<128, 256, 0, stream>>>(convAB, 7, 3, 16, stats);
  k_apply_bf<<<1024, 256, 0, stream>>>(convAB, 7, 3, 16, stats, g1a, b1a, g1b, b1b, 64);
  k_gather<<<512, 256, 0, stream>>>(convAB, 128, 64, idxp, 20, xcat, 0, 3);

  // layer 2 (64->64 x2)
  k_gemm<0><<<dim3(128,1), 256, 0, stream>>>(xcat + 0, 512, wc2, 64, convAB, 128);
  k_stats_bf<<<128, 256, 0, stream>>>(convAB, 7, 3, 16, stats);
  k_apply_bf<<<1024, 256, 0, stream>>>(convAB, 7, 3, 16, stats, g2a, b2a, g2b, b2b, 64);
  k_gather<<<512, 256, 0, stream>>>(convAB, 128, 64, idxp, 40, xcat, 64, 3);

  // layer 3 (64->128 x2, groups 8 => Cg 16, combined 16 groups)
  k_gemm<0><<<dim3(128,2), 256, 0, stream>>>(xcat + 64, 512, wc3, 64, convAB, 256);
  k_stats_bf<<<128, 256, 0, stream>>>(convAB, 8, 4, 16, stats);
  k_apply_bf<<<2048, 256, 0, stream>>>(convAB, 8, 4, 16, stats, g3a, b3a, g3b, b3b, 128);
  k_gather<<<1024, 256, 0, stream>>>(convAB, 256, 128, idxp, 60, xcat, 128, 4);

  // layer 4 (128->256 x2, groups 16 => Cg 16, combined 32 groups)
  k_gemm<0><<<dim3(128,4), 256, 0, stream>>>(xcat + 128, 512, wc4, 128, convAB, 512);
  k_stats_bf<<<256, 256, 0, stream>>>(convAB, 9, 4, 32, stats);
  k_apply_bf<<<4096, 256, 0, stream>>>(convAB, 9, 4, 32, stats, g4a, b4a, g4b, b4b, 256);
  k_gather<<<2048, 256, 0, stream>>>(convAB, 512, 256, idxp, 80, xcat, 256, 5);

  // layer 5_1 (512->1024, groups 16 => Cg 64)
  k_gemm<0><<<dim3(128,8), 256, 0, stream>>>(xcat, 512, w51b, 512, h1, 1024);
  k_stats_bf<<<128, 256, 0, stream>>>(h1, 10, 6, 16, stats);
  k_apply_bf<<<8192, 256, 0, stream>>>(h1, 10, 6, 16, stats, g51, b51, g51, b51, 1024);

  // layer 5_2 (1024->512, groups 16 => Cg 32), fp32 out in d_out, GN+LReLU in place
  k_gemm<1><<<dim3(128,4), 256, 0, stream>>>(h1, 1024, w52b, 1024, (void*)outf, 512);
  k_stats_f32<<<128, 256, 0, stream>>>(outf, 9, 5, 16, stats);
  k_apply_f32<<<8192, 256, 0, stream>>>(outf, 16, 5, stats, g52, b52);
}

// Round 4
// 497.239 us; speedup vs baseline: 1.2755x; 1.0092x over previous
//
#include <hip/hip_runtime.h>
#include <stdint.h>

typedef unsigned short u16;
typedef unsigned int u32;
typedef unsigned long long u64;
typedef __attribute__((ext_vector_type(8))) __bf16 bf16x8;
typedef __attribute__((ext_vector_type(8))) u16 u16x8;
typedef __attribute__((ext_vector_type(4))) float f32x4;

#define DEVI __device__ __forceinline__

DEVI u16 f2bf(float f) {                    // fp32 -> bf16 RNE
  u32 u = __float_as_uint(f);
  u += 0x7FFFu + ((u >> 16) & 1u);
  return (u16)(u >> 16);
}
DEVI float bf2f(u16 h) { return __uint_as_float(((u32)h) << 16); }
DEVI u16 mono(u16 b) {                      // order-isomorphic bf16 -> u16
  return (b & 0x8000u) ? (u16)~b : (u16)(b | 0x8000u);
}
DEVI u16 unmono(u16 t) {
  return (t & 0x8000u) ? (u16)(t ^ 0x8000u) : (u16)(~t);
}

DEVI float wredf(float v) {
  #pragma unroll
  for (int m = 32; m; m >>= 1) v += __shfl_xor(v, m, 64);
  return v;
}

DEVI void glds16(const void* g, void* l) {  // 16B-per-lane global->LDS DMA
  __builtin_amdgcn_global_load_lds((const __attribute__((address_space(1))) void*)g,
                                   (__attribute__((address_space(3))) void*)l, 16, 0, 0);
}

// ---------------- prep: pack (x,y,z,||x||^2) per point ----------------
__global__ void k_pack_coords(const float* __restrict__ x, float4* __restrict__ c4) {
  int g = blockIdx.x * 256 + threadIdx.x;          // < 16384
  float x0 = x[g*3], x1 = x[g*3+1], x2 = x[g*3+2];
  float n = __fadd_rn(__fadd_rn(__fmul_rn(x0,x0), __fmul_rn(x1,x1)), __fmul_rn(x2,x2));
  c4[g] = make_float4(x0, x1, x2, n);
}

// ---------------- prep: all MFMA weights -> bf16 (a/b stacked) ----------------
__global__ void k_pack_w(const float* __restrict__ w2a, const float* __restrict__ w2b,
                         const float* __restrict__ w3a, const float* __restrict__ w3b,
                         const float* __restrict__ w4a, const float* __restrict__ w4b,
                         const float* __restrict__ w51, const float* __restrict__ w52,
                         u16* __restrict__ wbf) {
  int g = blockIdx.x * 256 + threadIdx.x;          // < 1,138,688 exact
  const float* s; int off;
  if      (g <    4096) { s = w2a; off = g; }
  else if (g <    8192) { s = w2b; off = g - 4096; }
  else if (g <   16384) { s = w3a; off = g - 8192; }
  else if (g <   24576) { s = w3b; off = g - 16384; }
  else if (g <   57344) { s = w4a; off = g - 24576; }
  else if (g <   90112) { s = w4b; off = g - 57344; }
  else if (g <  614400) { s = w51; off = g - 90112; }
  else                  { s = w52; off = g - 614400; }
  wbf[g] = f2bf(s[off]);
}

// ---------------- knn: per-row top-80 (sorted desc, ties by low index) ----------------
// 4 independent query-waves per block, NO barriers (cand[wid] is wave-private).
// Ballot-count radix bisect with [80,128] early break; ballot-prefix compaction;
// 128-elem bitonic sort in registers via shfl_xor (2 u64/lane).
__global__ __launch_bounds__(256) void k_knn(const float4* __restrict__ c4, int* __restrict__ idxp) {
  __shared__ u64 cand[4][128];
  const int wid = threadIdx.x >> 6;
  const int lane = threadIdx.x & 63;
  const int blk = blockIdx.x * 4 + wid;             // query id = b*2048 + n
  const int b = blk >> 11;
  const float4* cb = c4 + (b << 11);
  const float4 q = cb[blk & 2047];

  u32 key[32];
  #pragma unroll
  for (int s = 0; s < 32; ++s) {
    float4 c = cb[s*64 + lane];
    // match reference rounding: inner=((x0y0+x1y1)+x2y2); pd=(2*inner - xn2) - xm2 ; no fma
    float inner = __fadd_rn(__fadd_rn(__fmul_rn(q.x,c.x), __fmul_rn(q.y,c.y)), __fmul_rn(q.z,c.z));
    float pd = __fsub_rn(__fsub_rn(__fmul_rn(2.0f, inner), q.w), c.w);
    u32 bits = __float_as_uint(pd);
    key[s] = (bits & 0x80000000u) ? ~bits : (bits | 0x80000000u);
  }

  // radix-bisect: find T with 80 <= count(key >= T) <= 128 (early break),
  // else exact-80 refinement continues to bit 0.
  u32 T = 0;
  for (int bit = 30; bit >= 0; --bit) {
    u32 Tc = T | (1u << bit);
    int c = 0;
    #pragma unroll
    for (int s = 0; s < 32; ++s)
      c += __popcll(__ballot(key[s] >= Tc));
    if (c >= 80) { T = Tc; if (c <= 128) break; }
  }

  // zero-fill candidate buffer (wave-private slice, no block barrier needed)
  cand[wid][lane] = 0ull;
  cand[wid][lane + 64] = 0ull;
  asm volatile("s_waitcnt lgkmcnt(0)" ::: "memory");

  // compact survivors: unique positions via ballot prefix (deterministic)
  const u64 below = (lane == 0) ? 0ull : (~0ull >> (64 - lane));
  int base = 0;
  #pragma unroll
  for (int s = 0; s < 32; ++s) {
    u64 msk = __ballot(key[s] >= T);
    if (key[s] >= T) {
      int pos = base + (int)__popcll(msk & below);
      if (pos < 128)
        cand[wid][pos] = (((u64)key[s]) << 32) | (u32)(2047 - (s*64 + lane));
    }
    base += (int)__popcll(msk);
  }
  asm volatile("s_waitcnt lgkmcnt(0)" ::: "memory");

  // register bitonic sort of 128 (descending): slot0 = elem[lane], slot1 = elem[lane+64]
  u64 v0 = cand[wid][lane];
  u64 v1 = cand[wid][lane + 64];
  #pragma unroll
  for (int k2 = 2; k2 <= 128; k2 <<= 1) {
    #pragma unroll
    for (int j = k2 >> 1; j > 0; j >>= 1) {
      if (j == 64) {                                // cross-slot, in-lane (k2==128 only)
        u64 mx = v0 > v1 ? v0 : v1;
        u64 mn = v0 > v1 ? v1 : v0;
        v0 = mx; v1 = mn;                           // desc=((lane&128)==0)=true -> low keeps max
      } else {
        u64 p0 = __shfl_xor(v0, j, 64);
        u64 p1 = __shfl_xor(v1, j, 64);
        bool lowlane = ((lane & j) == 0);
        bool d0 = ((lane & k2) == 0);               // elem index = lane
        bool d1 = (((lane + 64) & k2) == 0);        // elem index = lane+64
        bool wm0 = (d0 == lowlane);
        bool wm1 = (d1 == lowlane);
        u64 mx0 = v0 > p0 ? v0 : p0, mn0 = v0 > p0 ? p0 : v0;
        u64 mx1 = v1 > p1 ? v1 : p1, mn1 = v1 > p1 ? p1 : v1;
        v0 = wm0 ? mx0 : mn0;
        v1 = wm1 ? mx1 : mn1;
      }
    }
  }

  // ranks: elem[lane]=rank lane (v0), elem[64+lane]=rank 64+lane (v1); emit top 80
  idxp[blk*80 + lane] = 2047 - (int)(u32)v0;
  if (lane < 16) idxp[blk*80 + 64 + lane] = 2047 - (int)(u32)v1;
}

// ---------------- layer 1 conv (K=3, fp32 exact) -> bf16, both a&b paths ----------------
__global__ void k_conv1(const float* __restrict__ x, const float* __restrict__ w1a,
                        const float* __restrict__ w1b, u16* __restrict__ out) {
  int g = blockIdx.x * 256 + threadIdx.x;          // < 16384*128
  int m = g >> 7, o = g & 127;
  const float* w = (o < 64) ? (w1a + 3*o) : (w1b + 3*(o-64));
  const float* xm = x + 3*m;
  float acc = w[0]*xm[0] + w[1]*xm[1] + w[2]*xm[2];
  out[g] = f2bf(acc);
}

// ---------------- GroupNorm stats (one block per (b,group), deterministic) ----------------
__global__ __launch_bounds__(256) void k_stats_bf(const u16* __restrict__ act, int CtotShift,
                                                  int CgShift, int NG, float2* __restrict__ stats) {
  int b = blockIdx.x / NG, g = blockIdx.x % NG;
  int w4s = CgShift - 2;
  int count4 = 2048 << w4s;
  float s = 0.f, ss = 0.f;
  const u16* base = act + (((size_t)(b << 11)) << CtotShift) + ((size_t)g << CgShift);
  for (int i = threadIdx.x; i < count4; i += 256) {
    int n = i >> w4s, cw = i & ((1 << w4s) - 1);
    ushort4 v = *(const ushort4*)(base + (((size_t)n) << CtotShift) + cw*4);
    float a0 = bf2f(v.x), a1 = bf2f(v.y), a2 = bf2f(v.z), a3 = bf2f(v.w);
    s  += a0 + a1 + a2 + a3;
    ss += a0*a0 + a1*a1 + a2*a2 + a3*a3;
  }
  s = wredf(s); ss = wredf(ss);
  __shared__ float red[8];
  int wid = threadIdx.x >> 6;
  if ((threadIdx.x & 63) == 0) { red[wid*2] = s; red[wid*2+1] = ss; }
  __syncthreads();
  if (threadIdx.x == 0) {
    float S = red[0]+red[2]+red[4]+red[6], SS = red[1]+red[3]+red[5]+red[7];
    float cnt = (float)(2048 << CgShift);
    float mean = S / cnt;
    float var = SS / cnt - mean*mean;
    stats[blockIdx.x] = make_float2(mean, rsqrtf(var + 1e-5f));
  }
}

__global__ __launch_bounds__(256) void k_stats_f32(const float* __restrict__ act, int CtotShift,
                                                   int CgShift, int NG, float2* __restrict__ stats) {
  int b = blockIdx.x / NG, g = blockIdx.x % NG;
  int w4s = CgShift - 2;
  int count4 = 2048 << w4s;
  float s = 0.f, ss = 0.f;
  const float* base = act + (((size_t)(b << 11)) << CtotShift) + ((size_t)g << CgShift);
  for (int i = threadIdx.x; i < count4; i += 256) {
    int n = i >> w4s, cw = i & ((1 << w4s) - 1);
    float4 v = *(const float4*)(base + (((size_t)n) << CtotShift) + cw*4);
    s  += v.x + v.y + v.z + v.w;
    ss += v.x*v.x + v.y*v.y + v.z*v.z + v.w*v.w;
  }
  s = wredf(s); ss = wredf(ss);
  __shared__ float red[8];
  int wid = threadIdx.x >> 6;
  if ((threadIdx.x & 63) == 0) { red[wid*2] = s; red[wid*2+1] = ss; }
  __syncthreads();
  if (threadIdx.x == 0) {
    float S = red[0]+red[2]+red[4]+red[6], SS = red[1]+red[3]+red[5]+red[7];
    float cnt = (float)(2048 << CgShift);
    float mean = S / cnt;
    float var = SS / cnt - mean*mean;
    stats[blockIdx.x] = make_float2(mean, rsqrtf(var + 1e-5f));
  }
}

// ---------------- GN apply + LeakyReLU, in place (bf16), split gamma/beta a|b ----------------
// Channels c < transformCa are stored monotone-transformed (u16, order-isomorphic
// to bf16 compare) so the gather can max in the integer domain with v_pk_max_u16.
__global__ __launch_bounds__(256) void k_apply_bf(u16* __restrict__ act, int CtotShift, int CgShift,
    int NG, const float2* __restrict__ stats, const float* __restrict__ ga, const float* __restrict__ ba,
    const float* __restrict__ gb, const float* __restrict__ bb, int Ca, int transformCa) {
  int gid = blockIdx.x * 256 + threadIdx.x;
  size_t e = (size_t)gid * 8;
  int Ctot = 1 << CtotShift;
  int row = (int)(e >> CtotShift);
  int c = (int)e & (Ctot - 1);
  int g = c >> CgShift;
  float2 st = stats[(row >> 11) * NG + g];
  uint4 v = *(const uint4*)(act + e);
  u32 vv[4] = {v.x, v.y, v.z, v.w};
  #pragma unroll
  for (int q2 = 0; q2 < 4; ++q2) {
    int c0 = c + q2*2, c1 = c0 + 1;
    float x0 = bf2f((u16)(vv[q2] & 0xFFFF));
    float x1 = bf2f((u16)(vv[q2] >> 16));
    float G0 = (c0 < Ca) ? ga[c0] : gb[c0 - Ca];
    float B0 = (c0 < Ca) ? ba[c0] : bb[c0 - Ca];
    float G1 = (c1 < Ca) ? ga[c1] : gb[c1 - Ca];
    float B1 = (c1 < Ca) ? ba[c1] : bb[c1 - Ca];
    float h0 = (x0 - st.x) * st.y * G0 + B0;
    float h1 = (x1 - st.x) * st.y * G1 + B1;
    h0 = h0 > 0.f ? h0 : 0.2f * h0;
    h1 = h1 > 0.f ? h1 : 0.2f * h1;
    u16 r0 = f2bf(h0), r1 = f2bf(h1);
    if (c0 < transformCa) r0 = mono(r0);
    if (c1 < transformCa) r1 = mono(r1);
    vv[q2] = (u32)r0 | (((u32)r1) << 16);
  }
  *(uint4*)(act + e) = make_uint4(vv[0], vv[1], vv[2], vv[3]);
}

__global__ __launch_bounds__(256) void k_apply_f32(float* __restrict__ act, int NG, int CgShift,
    const float2* __restrict__ stats, const float* __restrict__ ga, const float* __restrict__ ba) {
  int gid = blockIdx.x * 256 + threadIdx.x;
  size_t e = (size_t)gid * 4;
  int row = (int)(e >> 9);               // Ctot = 512
  int c = (int)e & 511;
  int g = c >> CgShift;
  float2 st = stats[(row >> 11) * NG + g];
  float4 v = *(const float4*)(act + e);
  float h[4] = {v.x, v.y, v.z, v.w};
  #pragma unroll
  for (int q = 0; q < 4; ++q) {
    float xn = (h[q] - st.x) * st.y;
    float o = xn * ga[c+q] + ba[c+q];
    h[q] = o > 0.f ? o : 0.2f * o;
  }
  *(float4*)(act + e) = make_float4(h[0], h[1], h[2], h[3]);
}

// ---------------- gather-max over k neighbors + add fb -> xcat slice ----------------
// Batch->XCD pinned (batch = blockIdx.x & 7). fa rows are monotone-u16; the max
// runs as packed unsigned max (v_pk_max_u16), inverse-transformed once at the end.
__global__ __launch_bounds__(256) void k_gather(const u16* __restrict__ conv, int Ctot, int Ca,
    const int* __restrict__ idxp, int k, u16* __restrict__ xcat, int outOff, int lppShift) {
  const int batch = blockIdx.x & 7;
  const int blkin = blockIdx.x >> 3;
  const int lgid = blkin * 256 + threadIdx.x;        // within batch
  const int p_in = lgid >> lppShift;                 // point within batch, < 2048
  const int c8 = (lgid & ((1 << lppShift) - 1)) * 8; // channel offset (8 u16 per lane)
  const int p = (batch << 11) + p_in;
  const int* irow = idxp + (size_t)p * 80;
  const u16* cb = conv + ((size_t)(batch << 11)) * Ctot + c8;

  // fb read issued early (independent of gather chain); fb is plain bf16
  u16x8 fbv = *(const u16x8*)(conv + (size_t)p * Ctot + Ca + c8);

  u16x8 m8 = (u16x8)(u16)0;                          // 0 is identity in mono domain
  for (int j0 = 0; j0 < k; j0 += 4) {
    int4 mi4 = *(const int4*)(irow + j0);
    int mis[4] = {mi4.x, mi4.y, mi4.z, mi4.w};
    u16x8 rows[4];
    #pragma unroll
    for (int u = 0; u < 4; ++u)
      rows[u] = *(const u16x8*)(cb + (size_t)mis[u] * Ctot);
    #pragma unroll
    for (int u = 0; u < 4; ++u)
      m8 = __builtin_elementwise_max(m8, rows[u]);   // v_pk_max_u16 x4
  }

  u16 ov[8];
  #pragma unroll
  for (int q = 0; q < 8; ++q) {
    float mv = bf2f(unmono((u16)m8[q]));
    ov[q] = f2bf(mv + bf2f((u16)fbv[q]));
  }
  *(u16x8*)(xcat + (size_t)p * 512 + outOff + c8) = *(u16x8*)ov;
}

// ---------------- bf16 MFMA GEMM: C[M x N] = A[M x K] * W[N x K]^T ----------------
template<int OUTF32>
__global__ __launch_bounds__(256) void k_gemm(const u16* __restrict__ A, int lda,
    const u16* __restrict__ Bw, int K, void* __restrict__ outp, int ldc) {
  constexpr int BK = 64;
  __shared__ __align__(16) u16 As[128 * BK];
  __shared__ __align__(16) u16 Bs[128 * BK];
  const int tid = threadIdx.x;
  const int wid = tid >> 6, lane = tid & 63;
  const int tileM = blockIdx.x * 128, tileN = blockIdx.y * 128;
  const int wm = wid >> 1, wn = wid & 1;           // 2x2 waves, 64x64 each
  const int lr = lane & 15, lk = (lane >> 4) * 8;
  f32x4 acc[4][4] = {};
  for (int k0 = 0; k0 < K; k0 += BK) {
    __syncthreads();
    #pragma unroll
    for (int i = 0; i < 4; ++i) {
      int flat = i * 256 + tid;
      int row = flat >> 3, ck = flat & 7;
      glds16(A + (size_t)(tileM + row) * lda + (k0 + ck * 8), (char*)As + flat * 16);
    }
    #pragma unroll
    for (int i = 0; i < 4; ++i) {
      int flat = i * 256 + tid;
      int row = flat >> 3, ck = flat & 7;
      glds16(Bw + (size_t)(tileN + row) * K + (k0 + ck * 8), (char*)Bs + flat * 16);
    }
    __syncthreads();                                // drains vmcnt before barrier
    #pragma unroll
    for (int ks = 0; ks < 2; ++ks) {
      bf16x8 af[4], bfr[4];
      #pragma unroll
      for (int i = 0; i < 4; ++i)
        af[i] = *(const bf16x8*)&As[(wm*64 + i*16 + lr) * BK + ks*32 + lk];
      #pragma unroll
      for (int j = 0; j < 4; ++j)
        bfr[j] = *(const bf16x8*)&Bs[(wn*64 + j*16 + lr) * BK + ks*32 + lk];
      #pragma unroll
      for (int i = 0; i < 4; ++i)
        #pragma unroll
        for (int j = 0; j < 4; ++j)
          acc[i][j] = __builtin_amdgcn_mfma_f32_16x16x32_bf16(af[i], bfr[j], acc[i][j], 0, 0, 0);
    }
  }
  const int orow0 = tileM + wm*64 + ((lane >> 4) * 4);
  const int ocol0 = tileN + wn*64 + lr;
  #pragma unroll
  for (int i = 0; i < 4; ++i)
    #pragma unroll
    for (int j = 0; j < 4; ++j)
      #pragma unroll
      for (int r = 0; r < 4; ++r) {
        int row = orow0 + i*16 + r;
        int col = ocol0 + j*16;
        float v = acc[i][j][r];
        if (OUTF32) ((float*)outp)[(size_t)row * ldc + col] = v;
        else        ((u16*)outp)[(size_t)row * ldc + col] = f2bf(v);
      }
}

// ---------------- launch ----------------
extern "C" void kernel_launch(void* const* d_in, const int* in_sizes, int n_in,
                              void* d_out, int out_size, void* d_ws, size_t ws_size,
                              hipStream_t stream) {
  const float* x   = (const float*)d_in[0];
  const float* w1a = (const float*)d_in[1];
  const float* g1a = (const float*)d_in[2];
  const float* b1a = (const float*)d_in[3];
  const float* w1b = (const float*)d_in[4];
  const float* g1b = (const float*)d_in[5];
  const float* b1b = (const float*)d_in[6];
  const float* w2a = (const float*)d_in[7];
  const float* g2a = (const float*)d_in[8];
  const float* b2a = (const float*)d_in[9];
  const float* w2b = (const float*)d_in[10];
  const float* g2b = (const float*)d_in[11];
  const float* b2b = (const float*)d_in[12];
  const float* w3a = (const float*)d_in[13];
  const float* g3a = (const float*)d_in[14];
  const float* b3a = (const float*)d_in[15];
  const float* w3b = (const float*)d_in[16];
  const float* g3b = (const float*)d_in[17];
  const float* b3b = (const float*)d_in[18];
  const float* w4a = (const float*)d_in[19];
  const float* g4a = (const float*)d_in[20];
  const float* b4a = (const float*)d_in[21];
  const float* w4b = (const float*)d_in[22];
  const float* g4b = (const float*)d_in[23];
  const float* b4b = (const float*)d_in[24];
  const float* w51 = (const float*)d_in[25];
  const float* g51 = (const float*)d_in[26];
  const float* b51 = (const float*)d_in[27];
  const float* w52 = (const float*)d_in[28];
  const float* g52 = (const float*)d_in[29];
  const float* b52 = (const float*)d_in[30];

  char* ws = (char*)d_ws;                           // ~75 MB used
  int*    idxp   = (int*)   (ws + 0);               // 16384*80*4   = 5,242,880
  float4* c4     = (float4*)(ws + 5242880);         // 16384*16     = 262,144
  u16*    wbf    = (u16*)   (ws + 5505024);         // 1,138,688*2  = 2,277,376
  float2* stats  = (float2*)(ws + 7782400);         // 256*8        = 2,048
  u16*    convAB = (u16*)   (ws + 7784448);         // 16 MB
  u16*    h1     = (u16*)   (ws + 24561664);        // 32 MB
  u16*    xcat   = (u16*)   (ws + 58116096);        // 16 MB
  u16* wc2 = wbf, *wc3 = wbf + 8192, *wc4 = wbf + 24576;
  u16* w51b = wbf + 90112, *w52b = wbf + 614400;
  float* outf = (float*)d_out;

  k_pack_coords<<<64, 256, 0, stream>>>(x, c4);
  k_pack_w<<<4448, 256, 0, stream>>>(w2a, w2b, w3a, w3b, w4a, w4b, w51, w52, wbf);
  k_knn<<<4096, 256, 0, stream>>>(c4, idxp);

  // layer 1 (3->64 x2, groups 8 each => combined 16 groups of 8)
  k_conv1<<<8192, 256, 0, stream>>>(x, w1a, w1b, convAB);
  k_stats_bf<<<128, 256, 0, stream>>>(convAB, 7, 3, 16, stats);
  k_apply_bf<<<1024, 256, 0, stream>>>(convAB, 7, 3, 16, stats, g1a, b1a, g1b, b1b, 64, 64);
  k_gather<<<512, 256, 0, stream>>>(convAB, 128, 64, idxp, 20, xcat, 0, 3);

  // layer 2 (64->64 x2)
  k_gemm<0><<<dim3(128,1), 256, 0, stream>>>(xcat + 0, 512, wc2, 64, convAB, 128);
  k_stats_bf<<<128, 256, 0, stream>>>(convAB, 7, 3, 16, stats);
  k_apply_bf<<<1024, 256, 0, stream>>>(convAB, 7, 3, 16, stats, g2a, b2a, g2b, b2b, 64, 64);
  k_gather<<<512, 256, 0, stream>>>(convAB, 128, 64, idxp, 40, xcat, 64, 3);

  // layer 3 (64->128 x2, groups 8 => Cg 16, combined 16 groups)
  k_gemm<0><<<dim3(128,2), 256, 0, stream>>>(xcat + 64, 512, wc3, 64, convAB, 256);
  k_stats_bf<<<128, 256, 0, stream>>>(convAB, 8, 4, 16, stats);
  k_apply_bf<<<2048, 256, 0, stream>>>(convAB, 8, 4, 16, stats, g3a, b3a, g3b, b3b, 128, 128);
  k_gather<<<1024, 256, 0, stream>>>(convAB, 256, 128, idxp, 60, xcat, 128, 4);

  // layer 4 (128->256 x2, groups 16 => Cg 16, combined 32 groups)
  k_gemm<0><<<dim3(128,4), 256, 0, stream>>>(xcat + 128, 512, wc4, 128, convAB, 512);
  k_stats_bf<<<256, 256, 0, stream>>>(convAB, 9, 4, 32, stats);
  k_apply_bf<<<4096, 256, 0, stream>>>(convAB, 9, 4, 32, stats, g4a, b4a, g4b, b4b, 256, 256);
  k_gather<<<2048, 256, 0, stream>>>(convAB, 512, 256, idxp, 80, xcat, 256, 5);

  // layer 5_1 (512->1024, groups 16 => Cg 64) — no transform (no gather follows)
  k_gemm<0><<<dim3(128,8), 256, 0, stream>>>(xcat, 512, w51b, 512, h1, 1024);
  k_stats_bf<<<128, 256, 0, stream>>>(h1, 10, 6, 16, stats);
  k_apply_bf<<<8192, 256, 0, stream>>>(h1, 10, 6, 16, stats, g51, b51, g51, b51, 1024, 0);

  // layer 5_2 (1024->512, groups 16 => Cg 32), fp32 out in d_out, GN+LReLU in place
  k_gemm<1><<<dim3(128,4), 256, 0, stream>>>(h1, 1024, w52b, 1024, (void*)outf, 512);
  k_stats_f32<<<128, 256, 0, stream>>>(outf, 9, 5, 16, stats);
  k_apply_f32<<<8192, 256, 0, stream>>>(outf, 16, 5, stats, g52, b52);
}

// Round 5
// 280.617 us; speedup vs baseline: 2.2601x; 1.7719x over previous
//
#include <hip/hip_runtime.h>
#include <stdint.h>

typedef unsigned short u16;
typedef unsigned int u32;
typedef unsigned long long u64;
typedef __attribute__((ext_vector_type(8))) __bf16 bf16x8;
typedef __attribute__((ext_vector_type(8))) u16 u16x8;
typedef __attribute__((ext_vector_type(4))) float f32x4;

#define DEVI __device__ __forceinline__

DEVI u16 f2bf(float f) {                    // fp32 -> bf16 RNE
  u32 u = __float_as_uint(f);
  u += 0x7FFFu + ((u >> 16) & 1u);
  return (u16)(u >> 16);
}
DEVI float bf2f(u16 h) { return __uint_as_float(((u32)h) << 16); }
DEVI u16 mono(u16 b) {                      // order-isomorphic bf16 -> u16
  return (b & 0x8000u) ? (u16)~b : (u16)(b | 0x8000u);
}
DEVI u16 unmono(u16 t) {
  return (t & 0x8000u) ? (u16)(t ^ 0x8000u) : (u16)(~t);
}

DEVI void glds16(const void* g, void* l) {  // 16B-per-lane global->LDS DMA
  __builtin_amdgcn_global_load_lds((const __attribute__((address_space(1))) void*)g,
                                   (__attribute__((address_space(3))) void*)l, 16, 0, 0);
}

// ---------------- zero the fused-stats accumulators (run first every launch) ----------------
__global__ void k_zero(float* __restrict__ p, int n) {
  int i = blockIdx.x * 256 + threadIdx.x;
  if (i < n) p[i] = 0.f;
}

// ---------------- prep: pack (x,y,z,||x||^2) per point ----------------
__global__ void k_pack_coords(const float* __restrict__ x, float4* __restrict__ c4) {
  int g = blockIdx.x * 256 + threadIdx.x;          // < 16384
  float x0 = x[g*3], x1 = x[g*3+1], x2 = x[g*3+2];
  float n = __fadd_rn(__fadd_rn(__fmul_rn(x0,x0), __fmul_rn(x1,x1)), __fmul_rn(x2,x2));
  c4[g] = make_float4(x0, x1, x2, n);
}

// ---------------- prep: all MFMA weights -> bf16 (a/b stacked) ----------------
__global__ void k_pack_w(const float* __restrict__ w2a, const float* __restrict__ w2b,
                         const float* __restrict__ w3a, const float* __restrict__ w3b,
                         const float* __restrict__ w4a, const float* __restrict__ w4b,
                         const float* __restrict__ w51, const float* __restrict__ w52,
                         u16* __restrict__ wbf) {
  int g = blockIdx.x * 256 + threadIdx.x;          // < 1,138,688 exact
  const float* s; int off;
  if      (g <    4096) { s = w2a; off = g; }
  else if (g <    8192) { s = w2b; off = g - 4096; }
  else if (g <   16384) { s = w3a; off = g - 8192; }
  else if (g <   24576) { s = w3b; off = g - 16384; }
  else if (g <   57344) { s = w4a; off = g - 24576; }
  else if (g <   90112) { s = w4b; off = g - 57344; }
  else if (g <  614400) { s = w51; off = g - 90112; }
  else                  { s = w52; off = g - 614400; }
  wbf[g] = f2bf(s[off]);
}

// ---------------- knn: per-row top-80 (sorted desc, ties by low index) ----------------
// Batch->XCD pinned (batch = blockIdx & 7). 4 independent query-waves per block,
// no block barriers. Ballot radix bisect w/ [80,128] early break; register bitonic sort.
__global__ __launch_bounds__(256) void k_knn(const float4* __restrict__ c4, int* __restrict__ idxp) {
  __shared__ u64 cand[4][128];
  const int wid = threadIdx.x >> 6;
  const int lane = threadIdx.x & 63;
  const int batch = blockIdx.x & 7;
  const int qib = (blockIdx.x >> 3) * 4 + wid;      // query within batch
  const int blk = (batch << 11) + qib;
  const float4* cb = c4 + (batch << 11);
  const float4 q = cb[qib];

  u32 key[32];
  #pragma unroll
  for (int s = 0; s < 32; ++s) {
    float4 c = cb[s*64 + lane];
    float inner = __fadd_rn(__fadd_rn(__fmul_rn(q.x,c.x), __fmul_rn(q.y,c.y)), __fmul_rn(q.z,c.z));
    float pd = __fsub_rn(__fsub_rn(__fmul_rn(2.0f, inner), q.w), c.w);
    u32 bits = __float_as_uint(pd);
    key[s] = (bits & 0x80000000u) ? ~bits : (bits | 0x80000000u);
  }

  u32 T = 0;
  for (int bit = 30; bit >= 0; --bit) {
    u32 Tc = T | (1u << bit);
    int c = 0;
    #pragma unroll
    for (int s = 0; s < 32; ++s)
      c += __popcll(__ballot(key[s] >= Tc));
    if (c >= 80) { T = Tc; if (c <= 128) break; }
  }

  cand[wid][lane] = 0ull;
  cand[wid][lane + 64] = 0ull;
  asm volatile("s_waitcnt lgkmcnt(0)" ::: "memory");

  const u64 below = (lane == 0) ? 0ull : (~0ull >> (64 - lane));
  int base = 0;
  #pragma unroll
  for (int s = 0; s < 32; ++s) {
    u64 msk = __ballot(key[s] >= T);
    if (key[s] >= T) {
      int pos = base + (int)__popcll(msk & below);
      if (pos < 128)
        cand[wid][pos] = (((u64)key[s]) << 32) | (u32)(2047 - (s*64 + lane));
    }
    base += (int)__popcll(msk);
  }
  asm volatile("s_waitcnt lgkmcnt(0)" ::: "memory");

  u64 v0 = cand[wid][lane];
  u64 v1 = cand[wid][lane + 64];
  #pragma unroll
  for (int k2 = 2; k2 <= 128; k2 <<= 1) {
    #pragma unroll
    for (int j = k2 >> 1; j > 0; j >>= 1) {
      if (j == 64) {
        u64 mx = v0 > v1 ? v0 : v1;
        u64 mn = v0 > v1 ? v1 : v0;
        v0 = mx; v1 = mn;
      } else {
        u64 p0 = __shfl_xor(v0, j, 64);
        u64 p1 = __shfl_xor(v1, j, 64);
        bool lowlane = ((lane & j) == 0);
        bool d0 = ((lane & k2) == 0);
        bool d1 = (((lane + 64) & k2) == 0);
        bool wm0 = (d0 == lowlane);
        bool wm1 = (d1 == lowlane);
        u64 mx0 = v0 > p0 ? v0 : p0, mn0 = v0 > p0 ? p0 : v0;
        u64 mx1 = v1 > p1 ? v1 : p1, mn1 = v1 > p1 ? p1 : v1;
        v0 = wm0 ? mx0 : mn0;
        v1 = wm1 ? mx1 : mn1;
      }
    }
  }

  idxp[blk*80 + lane] = 2047 - (int)(u32)v0;
  if (lane < 16) idxp[blk*80 + 64 + lane] = 2047 - (int)(u32)v1;
}

// ---------------- layer 1 conv (K=3, fp32) + fused stats, store mono' ----------------
// 128 blocks; block covers 128 points x 128 ch. Thread: channel c = tid&127,
// half = tid>>7 -> 64 points each. Weights in regs, x staged in LDS.
__global__ __launch_bounds__(256) void k_conv1(const float* __restrict__ x,
    const float* __restrict__ w1a, const float* __restrict__ w1b,
    const float* __restrict__ g1a, const float* __restrict__ g1b,
    u16* __restrict__ out, float* __restrict__ gsum) {
  __shared__ float xs[384];
  __shared__ float colsum[128], colss[128];
  const int tid = threadIdx.x;
  const int P0 = blockIdx.x * 128;
  for (int i = tid; i < 384; i += 256) xs[i] = x[P0*3 + i];
  if (tid < 128) { colsum[tid] = 0.f; colss[tid] = 0.f; }
  __syncthreads();

  const int c = tid & 127;
  const int half = tid >> 7;
  const float* w = (c < 64) ? (w1a + 3*c) : (w1b + 3*(c-64));
  float wx = w[0], wy = w[1], wz = w[2];
  float gam = (c < 64) ? g1a[c] : g1b[c-64];
  u16 flip = (gam < 0.f) ? (u16)0xFFFF : (u16)0;

  float s = 0.f, ss = 0.f;
  #pragma unroll 4
  for (int p_ = 0; p_ < 64; ++p_) {
    int p = (half << 6) + p_;
    float h = wx*xs[p*3] + wy*xs[p*3+1] + wz*xs[p*3+2];
    s += h; ss += h*h;
    out[(size_t)(P0 + p)*128 + c] = (u16)(mono(f2bf(h)) ^ flip);
  }
  atomicAdd(&colsum[c], s);
  atomicAdd(&colss[c], ss);
  __syncthreads();
  if (tid < 16) {                                   // 16 groups of 8 channels
    float gs = 0.f, gss = 0.f;
    #pragma unroll
    for (int q = 0; q < 8; ++q) { gs += colsum[tid*8+q]; gss += colss[tid*8+q]; }
    int b = blockIdx.x >> 4;
    atomicAdd(&gsum[(b*16 + tid)*2],   gs);
    atomicAdd(&gsum[(b*16 + tid)*2+1], gss);
  }
}

// ---------------- fused gather-max + GroupNorm + LeakyReLU + add-fb ----------------
// conv holds mono'(bf16(h_raw)) (sign-flipped by gamma) for both halves.
// Max in key domain == correct extremum of the monotone GN+LReLU map.
__global__ __launch_bounds__(256) void k_gather(const u16* __restrict__ conv, int Ctot, int Ca,
    int CgShift, int NG, const float* __restrict__ gsum,
    const float* __restrict__ ga, const float* __restrict__ ba,
    const float* __restrict__ gb, const float* __restrict__ bb,
    const int* __restrict__ idxp, int k,
    u16* __restrict__ xcat, int outOff, int lppShift) {
  const int batch = blockIdx.x & 7;
  const int blkin = blockIdx.x >> 3;
  const int lgid = blkin * 256 + threadIdx.x;
  const int p_in = lgid >> lppShift;
  const int c8 = (lgid & ((1 << lppShift) - 1)) * 8;
  const int p = (batch << 11) + p_in;
  const int* irow = idxp + (size_t)p * 80;
  const u16* cb = conv + ((size_t)(batch << 11)) * Ctot + c8;

  // group stats (fused sums -> mean/rstd)
  const int gia = c8 >> CgShift;
  const int gib = (Ca + c8) >> CgShift;
  const float cnt = (float)(2048 << CgShift);
  float2 sa = *(const float2*)(gsum + (size_t)(batch*NG + gia)*2);
  float2 sb = *(const float2*)(gsum + (size_t)(batch*NG + gib)*2);
  float meanA = sa.x / cnt, rstdA = rsqrtf(sa.y / cnt - meanA*meanA + 1e-5f);
  float meanB = sb.x / cnt, rstdB = rsqrtf(sb.y / cnt - meanB*meanB + 1e-5f);

  // gamma/beta (issued early)
  float gav[8], bav[8], gbv[8], bbv[8];
  *(float4*)&gav[0] = *(const float4*)(ga + c8); *(float4*)&gav[4] = *(const float4*)(ga + c8 + 4);
  *(float4*)&bav[0] = *(const float4*)(ba + c8); *(float4*)&bav[4] = *(const float4*)(ba + c8 + 4);
  *(float4*)&gbv[0] = *(const float4*)(gb + c8); *(float4*)&gbv[4] = *(const float4*)(gb + c8 + 4);
  *(float4*)&bbv[0] = *(const float4*)(bb + c8); *(float4*)&bbv[4] = *(const float4*)(bb + c8 + 4);

  // fb row (mono')
  u16x8 fbv = *(const u16x8*)(conv + (size_t)p * Ctot + Ca + c8);

  u16x8 m8 = (u16x8)(u16)0;                          // safe identity (all real keys > 0)
  for (int j0 = 0; j0 < k; j0 += 4) {
    int4 mi4 = *(const int4*)(irow + j0);
    int mis[4] = {mi4.x, mi4.y, mi4.z, mi4.w};
    u16x8 rows[4];
    #pragma unroll
    for (int u = 0; u < 4; ++u)
      rows[u] = *(const u16x8*)(cb + (size_t)mis[u] * Ctot);
    #pragma unroll
    for (int u = 0; u < 4; ++u)
      m8 = __builtin_elementwise_max(m8, rows[u]);   // v_pk_max_u16
  }

  u16 ov[8];
  #pragma unroll
  for (int q = 0; q < 8; ++q) {
    u16 fA = (gav[q] < 0.f) ? (u16)0xFFFF : (u16)0;
    u16 fB = (gbv[q] < 0.f) ? (u16)0xFFFF : (u16)0;
    float xa = bf2f(unmono((u16)((u16)m8[q] ^ fA)));
    float ha = (xa - meanA) * rstdA * gav[q] + bav[q];
    ha = ha > 0.f ? ha : 0.2f * ha;
    float xb = bf2f(unmono((u16)((u16)fbv[q] ^ fB)));
    float hb = (xb - meanB) * rstdB * gbv[q] + bbv[q];
    hb = hb > 0.f ? hb : 0.2f * hb;
    ov[q] = f2bf(ha + hb);
  }
  *(u16x8*)(xcat + (size_t)p * 512 + outOff + c8) = *(u16x8*)ov;
}

// ---------------- GN apply + LeakyReLU from fused sums (layer 5_1, bf16) ----------------
__global__ __launch_bounds__(256) void k_apply51(u16* __restrict__ act,
    const float* __restrict__ gsum, const float* __restrict__ g, const float* __restrict__ b) {
  int gid = blockIdx.x * 256 + threadIdx.x;
  size_t e = (size_t)gid * 8;
  int row = (int)(e >> 10);
  int c = (int)e & 1023;
  int grp = c >> 6;
  float2 s = *(const float2*)(gsum + (size_t)((row >> 11)*16 + grp)*2);
  const float cnt = 131072.f;                        // 2048 * 64
  float mean = s.x / cnt, rstd = rsqrtf(s.y / cnt - mean*mean + 1e-5f);
  uint4 v = *(const uint4*)(act + e);
  u32 vv[4] = {v.x, v.y, v.z, v.w};
  #pragma unroll
  for (int q2 = 0; q2 < 4; ++q2) {
    int c0 = c + q2*2, c1 = c0 + 1;
    float x0 = bf2f((u16)(vv[q2] & 0xFFFF));
    float x1 = bf2f((u16)(vv[q2] >> 16));
    float h0 = (x0 - mean) * rstd * g[c0] + b[c0];
    float h1 = (x1 - mean) * rstd * g[c1] + b[c1];
    h0 = h0 > 0.f ? h0 : 0.2f * h0;
    h1 = h1 > 0.f ? h1 : 0.2f * h1;
    vv[q2] = (u32)f2bf(h0) | (((u32)f2bf(h1)) << 16);
  }
  *(uint4*)(act + e) = make_uint4(vv[0], vv[1], vv[2], vv[3]);
}

// ---------------- GN apply + LeakyReLU from fused sums (layer 5_2, f32) ----------------
__global__ __launch_bounds__(256) void k_apply52(float* __restrict__ act,
    const float* __restrict__ gsum, const float* __restrict__ g, const float* __restrict__ b) {
  int gid = blockIdx.x * 256 + threadIdx.x;
  size_t e = (size_t)gid * 4;
  int row = (int)(e >> 9);
  int c = (int)e & 511;
  int grp = c >> 5;
  float2 s = *(const float2*)(gsum + (size_t)((row >> 11)*16 + grp)*2);
  const float cnt = 65536.f;                         // 2048 * 32
  float mean = s.x / cnt, rstd = rsqrtf(s.y / cnt - mean*mean + 1e-5f);
  float4 v = *(const float4*)(act + e);
  float h[4] = {v.x, v.y, v.z, v.w};
  #pragma unroll
  for (int q = 0; q < 4; ++q) {
    float o = (h[q] - mean) * rstd * g[c+q] + b[c+q];
    h[q] = o > 0.f ? o : 0.2f * o;
  }
  *(float4*)(act + e) = make_float4(h[0], h[1], h[2], h[3]);
}

// ---------------- bf16 MFMA GEMM + fused GN stats (+ mono' store) ----------------
// C[M x N] = A[M x K] * W[N x K]^T ; epilogue reduces per-column sums -> per-group
// atomics into gsum; MONO stores mono(bf16)^signflip(gamma) for the gather.
template<int OUTF32, int MONO>
__global__ __launch_bounds__(256) void k_gemm(const u16* __restrict__ A, int lda,
    const u16* __restrict__ Bw, int K, void* __restrict__ outp, int ldc,
    int CgShift, int NG, float* __restrict__ gsum,
    const float* __restrict__ ga, const float* __restrict__ gb, int Ca) {
  constexpr int BK = 64;
  __shared__ __align__(16) u16 As[128 * BK];
  __shared__ __align__(16) u16 Bs[128 * BK];
  __shared__ float colsum[128], colss[128];
  const int tid = threadIdx.x;
  const int wid = tid >> 6, lane = tid & 63;
  const int tileM = blockIdx.x * 128, tileN = blockIdx.y * 128;
  const int wm = wid >> 1, wn = wid & 1;
  const int lr = lane & 15, lk = (lane >> 4) * 8;
  f32x4 acc[4][4] = {};
  for (int k0 = 0; k0 < K; k0 += BK) {
    __syncthreads();
    #pragma unroll
    for (int i = 0; i < 4; ++i) {
      int flat = i * 256 + tid;
      int row = flat >> 3, ck = flat & 7;
      glds16(A + (size_t)(tileM + row) * lda + (k0 + ck * 8), (char*)As + flat * 16);
    }
    #pragma unroll
    for (int i = 0; i < 4; ++i) {
      int flat = i * 256 + tid;
      int row = flat >> 3, ck = flat & 7;
      glds16(Bw + (size_t)(tileN + row) * K + (k0 + ck * 8), (char*)Bs + flat * 16);
    }
    __syncthreads();
    #pragma unroll
    for (int ks = 0; ks < 2; ++ks) {
      bf16x8 af[4], bfr[4];
      #pragma unroll
      for (int i = 0; i < 4; ++i)
        af[i] = *(const bf16x8*)&As[(wm*64 + i*16 + lr) * BK + ks*32 + lk];
      #pragma unroll
      for (int j = 0; j < 4; ++j)
        bfr[j] = *(const bf16x8*)&Bs[(wn*64 + j*16 + lr) * BK + ks*32 + lk];
      #pragma unroll
      for (int i = 0; i < 4; ++i)
        #pragma unroll
        for (int j = 0; j < 4; ++j)
          acc[i][j] = __builtin_amdgcn_mfma_f32_16x16x32_bf16(af[i], bfr[j], acc[i][j], 0, 0, 0);
    }
  }
  const int orow0 = tileM + wm*64 + ((lane >> 4) * 4);
  const int ocol0 = tileN + wn*64 + lr;

  u16 flip[4] = {0,0,0,0};
  if (MONO) {
    #pragma unroll
    for (int j = 0; j < 4; ++j) {
      int colg = ocol0 + j*16;
      float gm = (colg < Ca) ? ga[colg] : gb[colg - Ca];
      flip[j] = (gm < 0.f) ? (u16)0xFFFF : (u16)0;
    }
  }

  float csum[4] = {0.f,0.f,0.f,0.f}, css[4] = {0.f,0.f,0.f,0.f};
  #pragma unroll
  for (int i = 0; i < 4; ++i)
    #pragma unroll
    for (int j = 0; j < 4; ++j)
      #pragma unroll
      for (int r = 0; r < 4; ++r) {
        int row = orow0 + i*16 + r;
        int col = ocol0 + j*16;
        float v = acc[i][j][r];
        csum[j] += v; css[j] += v*v;
        if (OUTF32) ((float*)outp)[(size_t)row * ldc + col] = v;
        else {
          u16 st = f2bf(v);
          if (MONO) st = (u16)(mono(st) ^ flip[j]);
          ((u16*)outp)[(size_t)row * ldc + col] = st;
        }
      }

  // cross-lane: combine the 4 lanes sharing lr (lane>>4 = 0..3)
  #pragma unroll
  for (int mask = 16; mask <= 32; mask <<= 1)
    #pragma unroll
    for (int j = 0; j < 4; ++j) {
      csum[j] += __shfl_xor(csum[j], mask, 64);
      css[j]  += __shfl_xor(css[j],  mask, 64);
    }
  if (tid < 128) { colsum[tid] = 0.f; colss[tid] = 0.f; }
  __syncthreads();
  if ((lane >> 4) == 0) {
    #pragma unroll
    for (int j = 0; j < 4; ++j) {
      int col = wn*64 + j*16 + lr;
      atomicAdd(&colsum[col], csum[j]);
      atomicAdd(&colss[col],  css[j]);
    }
  }
  __syncthreads();
  const int NGtile = 128 >> CgShift;
  if (tid < NGtile) {
    float s = 0.f, ss = 0.f;
    const int Cg = 1 << CgShift;
    for (int c0 = tid << CgShift; c0 < (tid << CgShift) + Cg; ++c0) { s += colsum[c0]; ss += colss[c0]; }
    int b = tileM >> 11;
    int gidx = (tileN >> CgShift) + tid;
    atomicAdd(&gsum[(size_t)(b*NG + gidx)*2],   s);
    atomicAdd(&gsum[(size_t)(b*NG + gidx)*2+1], ss);
  }
}

// ---------------- launch ----------------
extern "C" void kernel_launch(void* const* d_in, const int* in_sizes, int n_in,
                              void* d_out, int out_size, void* d_ws, size_t ws_size,
                              hipStream_t stream) {
  const float* x   = (const float*)d_in[0];
  const float* w1a = (const float*)d_in[1];
  const float* g1a = (const float*)d_in[2];
  const float* b1a = (const float*)d_in[3];
  const float* w1b = (const float*)d_in[4];
  const float* g1b = (const float*)d_in[5];
  const float* b1b = (const float*)d_in[6];
  const float* w2a = (const float*)d_in[7];
  const float* g2a = (const float*)d_in[8];
  const float* b2a = (const float*)d_in[9];
  const float* w2b = (const float*)d_in[10];
  const float* g2b = (const float*)d_in[11];
  const float* b2b = (const float*)d_in[12];
  const float* w3a = (const float*)d_in[13];
  const float* g3a = (const float*)d_in[14];
  const float* b3a = (const float*)d_in[15];
  const float* w3b = (const float*)d_in[16];
  const float* g3b = (const float*)d_in[17];
  const float* b3b = (const float*)d_in[18];
  const float* w4a = (const float*)d_in[19];
  const float* g4a = (const float*)d_in[20];
  const float* b4a = (const float*)d_in[21];
  const float* w4b = (const float*)d_in[22];
  const float* g4b = (const float*)d_in[23];
  const float* b4b = (const float*)d_in[24];
  const float* w51 = (const float*)d_in[25];
  const float* g51 = (const float*)d_in[26];
  const float* b51 = (const float*)d_in[27];
  const float* w52 = (const float*)d_in[28];
  const float* g52 = (const float*)d_in[29];
  const float* b52 = (const float*)d_in[30];

  char* ws = (char*)d_ws;
  int*    idxp   = (int*)   (ws + 0);               // 5,242,880
  float4* c4     = (float4*)(ws + 5242880);         // 262,144
  u16*    wbf    = (u16*)   (ws + 5505024);         // 2,277,376
  float*  gsum   = (float*) (ws + 7782400);         // 8,192 (1024 float2)
  u16*    convAB = (u16*)   (ws + 7790592);         // 16,777,216
  u16*    h1     = (u16*)   (ws + 24567808);        // 33,554,432
  u16*    xcat   = (u16*)   (ws + 58122240);        // 16,777,216
  u16* wc2 = wbf, *wc3 = wbf + 8192, *wc4 = wbf + 24576;
  u16* w51b = wbf + 90112, *w52b = wbf + 614400;
  float* outf = (float*)d_out;
  // gsum layer offsets (float2 units): L1:0 L2:128 L3:256 L4:384 L5_1:640 L5_2:768
  float* gsL1 = gsum;        float* gsL2 = gsum + 256;  float* gsL3 = gsum + 512;
  float* gsL4 = gsum + 768;  float* gs51 = gsum + 1280; float* gs52 = gsum + 1536;

  k_zero<<<7, 256, 0, stream>>>(gsum, 1792);
  k_pack_coords<<<64, 256, 0, stream>>>(x, c4);
  k_pack_w<<<4448, 256, 0, stream>>>(w2a, w2b, w3a, w3b, w4a, w4b, w51, w52, wbf);
  k_knn<<<4096, 256, 0, stream>>>(c4, idxp);

  // layer 1: fused conv+stats -> fused gather+GN
  k_conv1<<<128, 256, 0, stream>>>(x, w1a, w1b, g1a, g1b, convAB, gsL1);
  k_gather<<<512, 256, 0, stream>>>(convAB, 128, 64, 3, 16, gsL1,
                                    g1a, b1a, g1b, b1b, idxp, 20, xcat, 0, 3);

  // layer 2
  k_gemm<0,1><<<dim3(128,1), 256, 0, stream>>>(xcat + 0, 512, wc2, 64, convAB, 128,
                                               3, 16, gsL2, g2a, g2b, 64);
  k_gather<<<512, 256, 0, stream>>>(convAB, 128, 64, 3, 16, gsL2,
                                    g2a, b2a, g2b, b2b, idxp, 40, xcat, 64, 3);

  // layer 3
  k_gemm<0,1><<<dim3(128,2), 256, 0, stream>>>(xcat + 64, 512, wc3, 64, convAB, 256,
                                               4, 16, gsL3, g3a, g3b, 128);
  k_gather<<<1024, 256, 0, stream>>>(convAB, 256, 128, 4, 16, gsL3,
                                     g3a, b3a, g3b, b3b, idxp, 60, xcat, 128, 4);

  // layer 4
  k_gemm<0,1><<<dim3(128,4), 256, 0, stream>>>(xcat + 128, 512, wc4, 128, convAB, 512,
                                               4, 32, gsL4, g4a, g4b, 256);
  k_gather<<<2048, 256, 0, stream>>>(convAB, 512, 256, 4, 32, gsL4,
                                     g4a, b4a, g4b, b4b, idxp, 80, xcat, 256, 5);

  // layer 5_1 (512->1024): GEMM+stats -> apply
  k_gemm<0,0><<<dim3(128,8), 256, 0, stream>>>(xcat, 512, w51b, 512, h1, 1024,
                                               6, 16, gs51, g51, g51, 1024);
  k_apply51<<<8192, 256, 0, stream>>>(h1, gs51, g51, b51);

  // layer 5_2 (1024->512): GEMM(f32 out)+stats -> apply
  k_gemm<1,0><<<dim3(128,4), 256, 0, stream>>>(h1, 1024, w52b, 1024, (void*)outf, 512,
                                               5, 16, gs52, g52, g52, 512);
  k_apply52<<<8192, 256, 0, stream>>>(outf, gs52, g52, b52);
}